// Round 2
// baseline (493.066 us; speedup 1.0000x reference)
//
#include <hip/hip_runtime.h>
#include <hip/hip_bf16.h>

#define NFRAME 2
#define NATOMS 4096
#define NNEI 138
#define SEL0 46
#define N1 24
#define N2 48
#define N3 96
#define ROWLEN 97
// G region: NNEI*ROWLEN = 13386 floats, pad to multiple of 4 for float4-aligned d
#define DOFF 13388
#define GROFF (DOFF + NNEI * 4)          // 13940
#define SMEM_FLOATS (GROFF + 4 * N3)     // 14324 floats = 57296 bytes

__device__ __forceinline__ float fexp2(float x) {
#if __has_builtin(__builtin_amdgcn_exp2f)
    return __builtin_amdgcn_exp2f(x);
#else
    return exp2f(x);
#endif
}

__device__ __forceinline__ float frcp(float x) {
#if __has_builtin(__builtin_amdgcn_rcpf)
    return __builtin_amdgcn_rcpf(x);
#else
    return 1.0f / x;
#endif
}

// tanh(x) = 1 - 2/(exp(2x)+1); saturates to +/-1 for |x| large (inf-safe)
__device__ __forceinline__ float fast_tanh(float x) {
    float e = fexp2(x * 2.8853900817779268f);  // exp(2x) = 2^(2x*log2(e))
    return 1.0f - 2.0f * frcp(e + 1.0f);
}

__global__ __launch_bounds__(192) __attribute__((amdgpu_waves_per_eu(1, 2)))
void descrpt_sea_kernel(
    const float* __restrict__ coord,
    const float* __restrict__ davg,
    const float* __restrict__ dstd,
    const float* __restrict__ W1, const float* __restrict__ b1,
    const float* __restrict__ W2, const float* __restrict__ b2,
    const float* __restrict__ W3, const float* __restrict__ b3,
    const int* __restrict__ atype, const int* __restrict__ nlist,
    float* __restrict__ out)
{
    __shared__ float smem[SMEM_FLOATS];
    const int bid  = blockIdx.x;          // f*NATOMS + n
    const int f    = bid >> 12;           // NATOMS = 4096
    const int tid  = threadIdx.x;
    const int wid  = tid >> 6;
    const int lane = tid & 63;

    // lane -> neighbor mapping; each wave is segment-uniform:
    // wave0: i=0..45 (type 0), wave1: i=46..109 (type 1), wave2: i=110..137 (type 1)
    int i;
    bool active;
    if (wid == 0)      { i = lane;             active = (lane < SEL0); }
    else if (wid == 1) { i = SEL0 + lane;      active = true; }
    else               { i = SEL0 + 64 + lane; active = (i < NNEI); }
    const int tseg = __builtin_amdgcn_readfirstlane((wid == 0) ? 0 : 1);

    const float cx = coord[bid * 3 + 0];
    const float cy = coord[bid * 3 + 1];
    const float cz = coord[bid * 3 + 2];
    const int at = atype[bid];

    // ---- phase 1: environment matrix d (per-neighbor) ----
    float x = 0.0f;
    if (active) {
        const int nl = nlist[bid * NNEI + i];
        const float* nc = coord + ((size_t)f * NATOMS + (size_t)nl) * 3;
        float dx = nc[0] - cx, dy = nc[1] - cy, dz = nc[2] - cz;
        float rsq = dx * dx + dy * dy + dz * dz;
        float r = sqrtf(fmaxf(rsq, 1e-12f));
        float uu = (r - 0.5f) * (1.0f / 5.5f);
        float vv = uu * uu * uu * (uu * (-6.0f * uu + 15.0f) - 10.0f) + 1.0f;
        float sw = (r < 0.5f) ? 1.0f : ((r < 6.0f) ? vv : 0.0f);
        float rinv = frcp(r);
        float s = sw * rinv;
        float sor = s * rinv;
        const float* avg  = davg + ((size_t)at * NNEI + i) * 4;
        const float* stdp = dstd + ((size_t)at * NNEI + i) * 4;
        float d0 = (s        - avg[0]) / stdp[0];
        float d1 = (sor * dx - avg[1]) / stdp[1];
        float d2 = (sor * dy - avg[2]) / stdp[2];
        float d3 = (sor * dz - avg[3]) / stdp[3];
        x = d0;
        float4 dv; dv.x = d0; dv.y = d1; dv.z = d2; dv.w = d3;
        *reinterpret_cast<float4*>(&smem[DOFF + i * 4]) = dv;
    }

    // per-segment weights: wave-uniform base -> scalar loads
    const float* W1p = W1 + tseg * N1;
    const float* b1p = b1 + tseg * N1;
    const float* W2p = W2 + tseg * (N1 * N2);
    const float* b2p = b2 + tseg * N2;
    const float* W3p = W3 + tseg * (N2 * N3);
    const float* b3p = b3 + tseg * N3;

    if (active) {
        // ---- stage B: h1 = tanh(x*W1 + b1), fully register-resident ----
        float h1[N1];
        #pragma unroll
        for (int j = 0; j < N1; ++j)
            h1[j] = fast_tanh(fmaf(x, W1p[j], b1p[j]));

        // ---- stage C: x2 = concat(h1,h1) + tanh(h1@W2 + b2) ----
        float x2[N2];
        #pragma unroll
        for (int j = 0; j < N2; ++j) x2[j] = b2p[j];
        #pragma unroll
        for (int k = 0; k < N1; ++k) {
            const float hk = h1[k];
            #pragma unroll
            for (int j = 0; j < N2; ++j)
                x2[j] = fmaf(hk, W2p[k * N2 + j], x2[j]);
        }
        #pragma unroll
        for (int j = 0; j < N2; ++j) {
            const int jm = (j < N1) ? j : (j - N1);
            x2[j] = h1[jm] + fast_tanh(x2[j]);
        }

        // ---- stage D: G = concat(x2,x2) + tanh(x2@W3 + b3) ----
        float acc3[N3];
        #pragma unroll
        for (int j = 0; j < N3; ++j) acc3[j] = b3p[j];
        #pragma unroll
        for (int k = 0; k < N2; ++k) {
            const float xk = x2[k];
            #pragma unroll
            for (int j = 0; j < N3; ++j)
                acc3[j] = fmaf(xk, W3p[k * N3 + j], acc3[j]);
        }
        // write G row to LDS (stride 97 -> conflict-free scalar stores)
        float* row = &smem[i * ROWLEN];
        #pragma unroll
        for (int j = 0; j < N2; ++j) {
            row[j]      = x2[j] + fast_tanh(acc3[j]);
            row[j + N2] = x2[j] + fast_tanh(acc3[j + N2]);
        }
    }

    __syncthreads();

    // ---- gr[a][m] = sum_i d[i][a]*G[i][m] / NNEI ----
    {
        const int m  = tid % 96;
        const int a1 = tid / 96;   // 0 or 1
        const int a2 = a1 + 2;
        float s1 = 0.0f, s2 = 0.0f;
        #pragma unroll 2
        for (int ii = 0; ii < NNEI; ++ii) {
            float g  = smem[ii * ROWLEN + m];
            float da = smem[DOFF + ii * 4 + a1];
            float db = smem[DOFF + ii * 4 + a2];
            s1 = fmaf(da, g, s1);
            s2 = fmaf(db, g, s2);
        }
        const float inv = 1.0f / (float)NNEI;
        smem[GROFF + a1 * 96 + m] = s1 * inv;
        smem[GROFF + a2 * 96 + m] = s2 * inv;
    }

    __syncthreads();

    // ---- D[m][k] = sum_a gr[a][m]*gr[a][k], k<8; coalesced store ----
    {
        const float* gr = &smem[GROFF];
        const size_t base = (size_t)bid * 768;
        #pragma unroll
        for (int rep = 0; rep < 4; ++rep) {
            const int o  = tid + rep * 192;
            const int mm = o >> 3;
            const int kk = o & 7;
            float acc = 0.0f;
            #pragma unroll
            for (int a = 0; a < 4; ++a)
                acc = fmaf(gr[a * 96 + mm], gr[a * 96 + kk], acc);
            out[base + o] = acc;
        }
    }
}

extern "C" void kernel_launch(void* const* d_in, const int* in_sizes, int n_in,
                              void* d_out, int out_size, void* d_ws, size_t ws_size,
                              hipStream_t stream) {
    const float* coord = (const float*)d_in[0];
    const float* davg  = (const float*)d_in[1];
    const float* dstd  = (const float*)d_in[2];
    const float* W1    = (const float*)d_in[3];
    const float* b1    = (const float*)d_in[4];
    const float* W2    = (const float*)d_in[5];
    const float* b2    = (const float*)d_in[6];
    const float* W3    = (const float*)d_in[7];
    const float* b3    = (const float*)d_in[8];
    const int*   atype = (const int*)d_in[9];
    const int*   nlist = (const int*)d_in[10];
    float* out = (float*)d_out;

    descrpt_sea_kernel<<<dim3(NFRAME * NATOMS), dim3(192), 0, stream>>>(
        coord, davg, dstd, W1, b1, W2, b2, W3, b3, atype, nlist, out);
}

// Round 3
// 350.053 us; speedup vs baseline: 1.4085x; 1.4085x over previous
//
#include <hip/hip_runtime.h>
#include <hip/hip_bf16.h>

#define NFRAME 2
#define NATOMS 4096
#define NNEI 138
#define SEL0 46
#define N1 24
#define N2 48
#define N3 96

// ---- LDS layout (float units) ----
// G quads: 24 m-quads x 139 rows x uint2 (4 bf16) = 24*139*2 floats
#define GQ_F 0
#define GQ_FLOATS (24 * 139 * 2)              // 6672
#define D4_F GQ_FLOATS                        // d: float4 per neighbor
#define D4_FLOATS (140 * 4)                   // 560
#define PART_F (D4_F + D4_FLOATS)             // 7232
#define PART_FLOATS (24 * 4 * 6 * 4)          // 2304
#define GR_F (PART_F + PART_FLOATS)           // 9536
#define SMEM_FLOATS (GR_F + 4 * 96)           // 9920 floats = 39680 B -> 4 blocks/CU

__device__ __forceinline__ float fexp2(float x) {
#if __has_builtin(__builtin_amdgcn_exp2f)
    return __builtin_amdgcn_exp2f(x);
#else
    return exp2f(x);
#endif
}

__device__ __forceinline__ float frcp(float x) {
#if __has_builtin(__builtin_amdgcn_rcpf)
    return __builtin_amdgcn_rcpf(x);
#else
    return 1.0f / x;
#endif
}

// tanh(x) = 1 - 2/(exp(2x)+1); saturates to +/-1 for |x| large (inf-safe)
__device__ __forceinline__ float fast_tanh(float x) {
    float e = fexp2(x * 2.8853900817779268f);
    return 1.0f - 2.0f * frcp(e + 1.0f);
}

// round-to-nearest-even f32 -> bf16 bits
__device__ __forceinline__ unsigned int f2bf(float f) {
    unsigned int u = __float_as_uint(f);
    return (u + 0x7fffu + ((u >> 16) & 1u)) >> 16;
}

__global__ __launch_bounds__(192) __attribute__((amdgpu_waves_per_eu(3)))
void descrpt_sea_kernel(
    const float* __restrict__ coord,
    const float* __restrict__ davg,
    const float* __restrict__ dstd,
    const float* __restrict__ W1, const float* __restrict__ b1,
    const float* __restrict__ W2, const float* __restrict__ b2,
    const float* __restrict__ W3, const float* __restrict__ b3,
    const int* __restrict__ atype, const int* __restrict__ nlist,
    float* __restrict__ out)
{
    __shared__ float smem[SMEM_FLOATS];
    const int bid  = blockIdx.x;          // f*NATOMS + n
    const int f    = bid >> 12;           // NATOMS = 4096
    const int tid  = threadIdx.x;
    const int wid  = tid >> 6;
    const int lane = tid & 63;

    // lane -> neighbor mapping; each wave is segment-uniform
    int i;
    bool active;
    if (wid == 0)      { i = lane;             active = (lane < SEL0); }
    else if (wid == 1) { i = SEL0 + lane;      active = true; }
    else               { i = SEL0 + 64 + lane; active = (i < NNEI); }
    const int tseg = __builtin_amdgcn_readfirstlane((wid == 0) ? 0 : 1);

    const float cx = coord[bid * 3 + 0];
    const float cy = coord[bid * 3 + 1];
    const float cz = coord[bid * 3 + 2];
    const int at = atype[bid];

    // ---- phase 1: environment matrix d ----
    float x = 0.0f;
    if (active) {
        const int nl = nlist[bid * NNEI + i];
        const float* nc = coord + ((size_t)f * NATOMS + (size_t)nl) * 3;
        float dx = nc[0] - cx, dy = nc[1] - cy, dz = nc[2] - cz;
        float rsq = dx * dx + dy * dy + dz * dz;
        float r = sqrtf(fmaxf(rsq, 1e-12f));
        float uu = (r - 0.5f) * (1.0f / 5.5f);
        float vv = uu * uu * uu * (uu * (-6.0f * uu + 15.0f) - 10.0f) + 1.0f;
        float sw = (r < 0.5f) ? 1.0f : ((r < 6.0f) ? vv : 0.0f);
        float rinv = frcp(r);
        float s = sw * rinv;
        float sor = s * rinv;
        const float* avg  = davg + ((size_t)at * NNEI + i) * 4;
        const float* stdp = dstd + ((size_t)at * NNEI + i) * 4;
        float d0 = (s        - avg[0]) / stdp[0];
        float d1 = (sor * dx - avg[1]) / stdp[1];
        float d2 = (sor * dy - avg[2]) / stdp[2];
        float d3 = (sor * dz - avg[3]) / stdp[3];
        x = d0;
        float4 dv; dv.x = d0; dv.y = d1; dv.z = d2; dv.w = d3;
        *reinterpret_cast<float4*>(&smem[D4_F + i * 4]) = dv;
    }

    // per-segment weights (wave-uniform -> scalar loads)
    const float* W1p = W1 + tseg * N1;
    const float* b1p = b1 + tseg * N1;
    const float* W2p = W2 + tseg * (N1 * N2);
    const float* b2p = b2 + tseg * N2;
    const float* W3p = W3 + tseg * (N2 * N3);
    const float* b3p = b3 + tseg * N3;

    if (active) {
        // ---- stage B: h1 = tanh(x*W1 + b1) ----
        float h1[N1];
        #pragma unroll
        for (int j = 0; j < N1; ++j)
            h1[j] = fast_tanh(fmaf(x, W1p[j], b1p[j]));

        // ---- stage C: x2 = concat(h1,h1) + tanh(h1@W2 + b2); k-outer, j contiguous ----
        float x2[N2];
        #pragma unroll
        for (int j = 0; j < N2; ++j) x2[j] = b2p[j];
        #pragma unroll
        for (int k = 0; k < N1; ++k) {
            const float hk = h1[k];
            #pragma unroll
            for (int j = 0; j < N2; ++j)
                x2[j] = fmaf(hk, W2p[k * N2 + j], x2[j]);
        }
        #pragma unroll
        for (int j = 0; j < N2; ++j) {
            const int jm = (j < N1) ? j : (j - N1);
            x2[j] = h1[jm] + fast_tanh(x2[j]);
        }

        // ---- stage D: two 48-wide j-tiles, k-outer; G -> LDS as bf16 quads ----
        uint2* gq = reinterpret_cast<uint2*>(&smem[GQ_F]);
        #pragma unroll
        for (int t = 0; t < 2; ++t) {
            float acc[48];
            #pragma unroll
            for (int j = 0; j < 48; ++j) acc[j] = b3p[t * 48 + j];
            #pragma unroll
            for (int k = 0; k < N2; ++k) {
                const float xk = x2[k];
                const float* wrow = W3p + k * N3 + t * 48;
                #pragma unroll
                for (int j = 0; j < 48; ++j)
                    acc[j] = fmaf(xk, wrow[j], acc[j]);
            }
            // G[t*48 + jj] = x2[jj] + tanh(acc[jj])  (both tiles reuse x2[jj])
            #pragma unroll
            for (int j4 = 0; j4 < 12; ++j4) {
                float g0 = x2[j4 * 4 + 0] + fast_tanh(acc[j4 * 4 + 0]);
                float g1 = x2[j4 * 4 + 1] + fast_tanh(acc[j4 * 4 + 1]);
                float g2 = x2[j4 * 4 + 2] + fast_tanh(acc[j4 * 4 + 2]);
                float g3 = x2[j4 * 4 + 3] + fast_tanh(acc[j4 * 4 + 3]);
                uint2 q;
                q.x = f2bf(g0) | (f2bf(g1) << 16);
                q.y = f2bf(g2) | (f2bf(g3) << 16);
                const int mq = t * 12 + j4;
                gq[mq * 139 + i] = q;
            }
        }
    }

    __syncthreads();

    // ---- phase 2a: partial gr; thread = (m-quad, i-slice); G read ONCE ----
    if (tid < 144) {
        const int mq    = tid % 24;
        const int slice = tid / 24;           // 0..5, 23 neighbors each
        const uint2* gq = reinterpret_cast<const uint2*>(&smem[GQ_F]) + mq * 139;
        float acc[4][4];
        #pragma unroll
        for (int a = 0; a < 4; ++a)
            #pragma unroll
            for (int m = 0; m < 4; ++m) acc[a][m] = 0.0f;

        for (int it = 0; it < 23; ++it) {
            const int ii = slice * 23 + it;
            const uint2 q = gq[ii];
            float g[4];
            g[0] = __uint_as_float(q.x << 16);
            g[1] = __uint_as_float(q.x & 0xffff0000u);
            g[2] = __uint_as_float(q.y << 16);
            g[3] = __uint_as_float(q.y & 0xffff0000u);
            const float4 dv = *reinterpret_cast<const float4*>(&smem[D4_F + ii * 4]);
            #pragma unroll
            for (int m = 0; m < 4; ++m) {
                acc[0][m] = fmaf(dv.x, g[m], acc[0][m]);
                acc[1][m] = fmaf(dv.y, g[m], acc[1][m]);
                acc[2][m] = fmaf(dv.z, g[m], acc[2][m]);
                acc[3][m] = fmaf(dv.w, g[m], acc[3][m]);
            }
        }
        #pragma unroll
        for (int a = 0; a < 4; ++a) {
            float4 v; v.x = acc[a][0]; v.y = acc[a][1]; v.z = acc[a][2]; v.w = acc[a][3];
            *reinterpret_cast<float4*>(&smem[PART_F + ((mq * 4 + a) * 6 + slice) * 4]) = v;
        }
    }

    __syncthreads();

    // ---- phase 2b: reduce slices -> gr[a][m] ----
    if (tid < 96) {
        const int mq = tid % 24;
        const int a  = tid / 24;
        float4 s0 = *reinterpret_cast<const float4*>(&smem[PART_F + ((mq * 4 + a) * 6 + 0) * 4]);
        #pragma unroll
        for (int sl = 1; sl < 6; ++sl) {
            const float4 p = *reinterpret_cast<const float4*>(&smem[PART_F + ((mq * 4 + a) * 6 + sl) * 4]);
            s0.x += p.x; s0.y += p.y; s0.z += p.z; s0.w += p.w;
        }
        const float inv = 1.0f / (float)NNEI;
        float4 g; g.x = s0.x * inv; g.y = s0.y * inv; g.z = s0.z * inv; g.w = s0.w * inv;
        *reinterpret_cast<float4*>(&smem[GR_F + a * 96 + mq * 4]) = g;
    }

    __syncthreads();

    // ---- phase 3: D[m][k] = sum_a gr[a][m]*gr[a][k], k<8 ----
    {
        const float* gr = &smem[GR_F];
        const size_t base = (size_t)bid * 768;
        #pragma unroll
        for (int rep = 0; rep < 4; ++rep) {
            const int o  = tid + rep * 192;
            const int mm = o >> 3;
            const int kk = o & 7;
            float acc = 0.0f;
            #pragma unroll
            for (int a = 0; a < 4; ++a)
                acc = fmaf(gr[a * 96 + mm], gr[a * 96 + kk], acc);
            out[base + o] = acc;
        }
    }
}

extern "C" void kernel_launch(void* const* d_in, const int* in_sizes, int n_in,
                              void* d_out, int out_size, void* d_ws, size_t ws_size,
                              hipStream_t stream) {
    const float* coord = (const float*)d_in[0];
    const float* davg  = (const float*)d_in[1];
    const float* dstd  = (const float*)d_in[2];
    const float* W1    = (const float*)d_in[3];
    const float* b1    = (const float*)d_in[4];
    const float* W2    = (const float*)d_in[5];
    const float* b2    = (const float*)d_in[6];
    const float* W3    = (const float*)d_in[7];
    const float* b3    = (const float*)d_in[8];
    const int*   atype = (const int*)d_in[9];
    const int*   nlist = (const int*)d_in[10];
    float* out = (float*)d_out;

    descrpt_sea_kernel<<<dim3(NFRAME * NATOMS), dim3(192), 0, stream>>>(
        coord, davg, dstd, W1, b1, W2, b2, W3, b3, atype, nlist, out);
}

// Round 5
// 171.237 us; speedup vs baseline: 2.8794x; 2.0443x over previous
//
#include <hip/hip_runtime.h>
#include <hip/hip_bf16.h>

#define NFRAME 2
#define NATOMS 4096
#define NNEI 138
#define SEL0 46
#define N1 24
#define N2 48
#define N3 96

// ---- LDS layout (BYTE offsets) ----
#define X2B 0                        // 144 rows x 96 B  : bf16 x2[48] per padded row
#define D4B 13824                    // 144 rows x 16 B  : float4 d per padded row
#define W3B 16128                    // 2 seg x 96 col x 128 B : bf16 W3^T, XOR-swizzled
#define GRPB 16128                   // alias into W3T (after barrier2): 3w x 4a x 96 x f32 = 4608
#define GRB (16128 + 4608)           // 4 x 96 f32 = 1536
#define SMEM_BYTES (16128 + 24576)   // 40704 B -> 4 blocks/CU

using short8 = __attribute__((ext_vector_type(8))) short;
using f32x4  = __attribute__((ext_vector_type(4))) float;

__device__ __forceinline__ float fexp2(float x) {
#if __has_builtin(__builtin_amdgcn_exp2f)
    return __builtin_amdgcn_exp2f(x);
#else
    return exp2f(x);
#endif
}
__device__ __forceinline__ float frcp(float x) {
#if __has_builtin(__builtin_amdgcn_rcpf)
    return __builtin_amdgcn_rcpf(x);
#else
    return 1.0f / x;
#endif
}
// tanh(x) = 1 - 2/(exp(2x)+1); saturates for |x| large
__device__ __forceinline__ float fast_tanh(float x) {
    float e = fexp2(x * 2.8853900817779268f);
    return 1.0f - 2.0f * frcp(e + 1.0f);
}
// RNE f32 -> bf16 bits
__device__ __forceinline__ unsigned int f2bf(float f) {
    unsigned int u = __float_as_uint(f);
    return (u + 0x7fffu + ((u >> 16) & 1u)) >> 16;
}
__device__ __forceinline__ float bf2f(unsigned int b) {
    return __uint_as_float(b << 16);
}

__global__ __launch_bounds__(192) __attribute__((amdgpu_waves_per_eu(3)))
void descrpt_sea_kernel(
    const float* __restrict__ coord,
    const float* __restrict__ davg,
    const float* __restrict__ dstd,
    const float* __restrict__ W1, const float* __restrict__ b1,
    const float* __restrict__ W2, const float* __restrict__ b2,
    const float* __restrict__ W3, const float* __restrict__ b3,
    const int* __restrict__ atype, const int* __restrict__ nlist,
    float* __restrict__ out)
{
    __shared__ float smemf[SMEM_BYTES / 4];
    unsigned char* smemb = reinterpret_cast<unsigned char*>(smemf);

    const int bid  = blockIdx.x;          // f*NATOMS + n
    const int f    = bid >> 12;
    const int tid  = threadIdx.x;
    const int wid  = tid >> 6;
    const int lane = tid & 63;
    const int cl   = lane & 15;
    const int grp  = lane >> 4;

    // lane -> neighbor; each wave segment-uniform.
    // padded rows: seg0 -> 0..45 (pad 46,47), seg1 -> 48..139 (pad 140..143)
    int i;
    bool active;
    if (wid == 0)      { i = lane;             active = (lane < SEL0); }
    else if (wid == 1) { i = SEL0 + lane;      active = true; }
    else               { i = SEL0 + 64 + lane; active = (i < NNEI); }
    const int tseg = __builtin_amdgcn_readfirstlane((wid == 0) ? 0 : 1);
    const int prow = (i < SEL0) ? i : (i + 2);

    const float cx = coord[bid * 3 + 0];
    const float cy = coord[bid * 3 + 1];
    const float cz = coord[bid * 3 + 2];
    const int at = atype[bid];

    // per-segment weight bases (wave-uniform -> s_load)
    const float* W1p = W1 + tseg * N1;
    const float* b1p = b1 + tseg * N1;
    const float* W2p = W2 + tseg * (N1 * N2);
    const float* b2p = b2 + tseg * N2;
    const float* b3p = b3 + tseg * N3;

    // per-lane b3 values for the 6 N-tiles (col = nt*16 + cl)
    float b3v[6];
    #pragma unroll
    for (int nt = 0; nt < 6; ++nt) b3v[nt] = b3p[nt * 16 + cl];

    // ---- W3^T staging: W3[2][48][96] f32 -> LDS bf16 [seg][col][k], XOR-swizzled ----
    #pragma unroll 4
    for (int it = 0; it < 48; ++it) {
        const int idx = it * 192 + tid;            // 0..9215, coalesced
        const int seg = idx / 4608;
        const int rem = idx - seg * 4608;
        const int k   = rem / 96;
        const int c   = rem - k * 96;
        const float v = W3[idx];
        const int off = ((seg * 96 + c) << 7) + ((k << 1) ^ ((c & 7) << 4));
        *reinterpret_cast<unsigned short*>(smemb + W3B + off) = (unsigned short)f2bf(v);
    }
    // NaN FIX: zero-fill the k=48..63 pad chunks of every W3T row (pre-swizzle
    // chunks 6,7 -> post-swizzle byte offsets 96^sw, 112^sw). Without this the
    // B-fragments for grp 2,3 read uninitialized LDS; 0 x NaN = NaN.
    {
        const int row = tid;                       // seg*96+c = 0..191
        const int c = row % 96;
        const int sw = (c & 7) << 4;
        uint4 z; z.x = 0u; z.y = 0u; z.z = 0u; z.w = 0u;
        *reinterpret_cast<uint4*>(smemb + W3B + (row << 7) + (96 ^ sw)) = z;
        *reinterpret_cast<uint4*>(smemb + W3B + (row << 7) + (112 ^ sw)) = z;
    }

    // ---- zero pad rows (X2 rows 46,47,140..143 ; d4 same rows) ----
    if (tid < 144) {
        const int ri = tid / 24;                   // 0..5
        const int row = (ri < 2) ? (46 + ri) : (138 + ri);
        *reinterpret_cast<unsigned int*>(smemb + X2B + row * 96 + (tid % 24) * 4) = 0u;
    }
    if (tid < 24) {
        const int ri = tid / 4;                    // 0..5
        const int row = (ri < 2) ? (46 + ri) : (138 + ri);
        *reinterpret_cast<unsigned int*>(smemb + D4B + row * 16 + (tid % 4) * 4) = 0u;
    }

    // ---- phase 1: environment matrix d ----
    float x = 0.0f;
    if (active) {
        const int nl = nlist[bid * NNEI + i];
        const float* nc = coord + ((size_t)f * NATOMS + (size_t)nl) * 3;
        float dx = nc[0] - cx, dy = nc[1] - cy, dz = nc[2] - cz;
        float rsq = dx * dx + dy * dy + dz * dz;
        float r = sqrtf(fmaxf(rsq, 1e-12f));
        float uu = (r - 0.5f) * (1.0f / 5.5f);
        float vv = uu * uu * uu * (uu * (-6.0f * uu + 15.0f) - 10.0f) + 1.0f;
        float sw = (r < 0.5f) ? 1.0f : ((r < 6.0f) ? vv : 0.0f);
        float rinv = frcp(r);
        float s = sw * rinv;
        float sor = s * rinv;
        const float* avg  = davg + ((size_t)at * NNEI + i) * 4;
        const float* stdp = dstd + ((size_t)at * NNEI + i) * 4;
        f32x4 dv;
        dv.x = (s        - avg[0]) / stdp[0];
        dv.y = (sor * dx - avg[1]) / stdp[1];
        dv.z = (sor * dy - avg[2]) / stdp[2];
        dv.w = (sor * dz - avg[3]) / stdp[3];
        x = dv.x;
        *reinterpret_cast<f32x4*>(smemb + D4B + prow * 16) = dv;

        // ---- stage B: h1 = tanh(x*W1 + b1) ----
        float h1[N1];
        #pragma unroll
        for (int j = 0; j < N1; ++j)
            h1[j] = fast_tanh(fmaf(x, W1p[j], b1p[j]));

        // ---- stage C: x2 = concat(h1,h1) + tanh(h1@W2 + b2) ----
        float x2[N2];
        #pragma unroll
        for (int j = 0; j < N2; ++j) x2[j] = b2p[j];
        #pragma unroll
        for (int k = 0; k < N1; ++k) {
            const float hk = h1[k];
            #pragma unroll
            for (int j = 0; j < N2; ++j)
                x2[j] = fmaf(hk, W2p[k * N2 + j], x2[j]);
        }
        #pragma unroll
        for (int j = 0; j < N2; ++j) {
            const int jm = (j < N1) ? j : (j - N1);
            x2[j] = h1[jm] + fast_tanh(x2[j]);
        }

        // ---- x2 -> bf16 -> X2 LDS row (6 x b128) ----
        #pragma unroll
        for (int c = 0; c < 6; ++c) {
            unsigned int u0 = f2bf(x2[c * 8 + 0]) | (f2bf(x2[c * 8 + 1]) << 16);
            unsigned int u1 = f2bf(x2[c * 8 + 2]) | (f2bf(x2[c * 8 + 3]) << 16);
            unsigned int u2 = f2bf(x2[c * 8 + 4]) | (f2bf(x2[c * 8 + 5]) << 16);
            unsigned int u3 = f2bf(x2[c * 8 + 6]) | (f2bf(x2[c * 8 + 7]) << 16);
            uint4 w; w.x = u0; w.y = u1; w.z = u2; w.w = u3;
            *reinterpret_cast<uint4*>(smemb + X2B + prow * 96 + c * 16) = w;
        }
    }

    __syncthreads();   // barrier 1: X2, d4, W3T complete

    // ---- load B-fragments (W3T) : 6 N-tiles x 2 k-steps ----
    short8 bk0[6], bk1[6];
    #pragma unroll
    for (int nt = 0; nt < 6; ++nt) {
        const int col = nt * 16 + cl;
        const int base = (tseg * 96 + col) << 7;
        const int sw = (col & 7) << 4;
        bk0[nt] = *reinterpret_cast<const short8*>(smemb + W3B + base + ((grp * 16) ^ sw));
        // k-step1: k = 32 + grp*8 + j ; grp 2,3 (k>=48) read the zero-filled pad
        bk1[nt] = *reinterpret_cast<const short8*>(smemb + W3B + base + ((64 + grp * 16) ^ sw));
    }

    __syncthreads();   // barrier 2: all W3T reads done -> GRPB alias safe

    // ---- MFMA: 3 M-tiles per wave x 6 N-tiles x 2 k-steps; C init = b3 bias ----
    f32x4 acc[3][6];
    #pragma unroll
    for (int mt = 0; mt < 3; ++mt)
        #pragma unroll
        for (int nt = 0; nt < 6; ++nt) {
            f32x4 c0; c0[0] = b3v[nt]; c0[1] = b3v[nt]; c0[2] = b3v[nt]; c0[3] = b3v[nt];
            acc[mt][nt] = c0;
        }

    const short8 zero8 = (short8){0,0,0,0,0,0,0,0};
    #pragma unroll
    for (int mt = 0; mt < 3; ++mt) {
        const int row = (wid * 3 + mt) * 16 + cl;
        const short8 a0 = *reinterpret_cast<const short8*>(smemb + X2B + row * 96 + grp * 16);
        short8 a1 = *reinterpret_cast<const short8*>(smemb + X2B + row * 96 + 64 + (grp & 1) * 16);
        a1 = (grp < 2) ? a1 : zero8;   // zero k=48..63
        #pragma unroll
        for (int nt = 0; nt < 6; ++nt) {
            acc[mt][nt] = __builtin_amdgcn_mfma_f32_16x16x32_bf16(a0, bk0[nt], acc[mt][nt], 0, 0, 0);
            acc[mt][nt] = __builtin_amdgcn_mfma_f32_16x16x32_bf16(a1, bk1[nt], acc[mt][nt], 0, 0, 0);
        }
    }

    // ---- epilogue: G = x2c + tanh(acc); gsum[a][nt] += d[row][a]*G ----
    float gsum[4][6];
    #pragma unroll
    for (int a = 0; a < 4; ++a)
        #pragma unroll
        for (int nt = 0; nt < 6; ++nt) gsum[a][nt] = 0.f;

    #pragma unroll
    for (int mt = 0; mt < 3; ++mt) {
        f32x4 dv[4];
        float x2v[4][3];
        #pragma unroll
        for (int q = 0; q < 4; ++q) {
            const int r = (wid * 3 + mt) * 16 + grp * 4 + q;
            dv[q] = *reinterpret_cast<const f32x4*>(smemb + D4B + r * 16);
            #pragma unroll
            for (int c0 = 0; c0 < 3; ++c0) {
                const unsigned short u =
                    *reinterpret_cast<const unsigned short*>(smemb + X2B + r * 96 + 2 * (c0 * 16 + cl));
                x2v[q][c0] = bf2f((unsigned int)u);
            }
        }
        #pragma unroll
        for (int nt = 0; nt < 6; ++nt) {
            const int c0 = (nt < 3) ? nt : (nt - 3);
            #pragma unroll
            for (int q = 0; q < 4; ++q) {
                const float g = x2v[q][c0] + fast_tanh(acc[mt][nt][q]);
                gsum[0][nt] = fmaf(dv[q].x, g, gsum[0][nt]);
                gsum[1][nt] = fmaf(dv[q].y, g, gsum[1][nt]);
                gsum[2][nt] = fmaf(dv[q].z, g, gsum[2][nt]);
                gsum[3][nt] = fmaf(dv[q].w, g, gsum[3][nt]);
            }
        }
    }

    // ---- cross-lane reduce over row-groups (lane^16, lane^32) ----
    float red[24];
    #pragma unroll
    for (int a = 0; a < 4; ++a) {
        #pragma unroll
        for (int nt = 0; nt < 6; ++nt) {
            float v = gsum[a][nt];
            v += __shfl_xor(v, 16, 64);
            v += __shfl_xor(v, 32, 64);
            red[a * 6 + nt] = v;
        }
    }
    if (lane < 16) {
        #pragma unroll
        for (int a = 0; a < 4; ++a)
            #pragma unroll
            for (int nt = 0; nt < 6; ++nt)
                *reinterpret_cast<float*>(smemb + GRPB +
                    (((wid * 4 + a) * 96) + nt * 16 + lane) * 4) = red[a * 6 + nt];
    }

    __syncthreads();   // barrier 3

    // ---- final gr = sum over 3 waves, /NNEI ----
    {
        const float inv = 1.0f / (float)NNEI;
        #pragma unroll
        for (int rep = 0; rep < 2; ++rep) {
            const int id = tid + rep * 192;        // 0..383
            const int a = id / 96;
            const int c = id - a * 96;
            float s = 0.f;
            #pragma unroll
            for (int w = 0; w < 3; ++w)
                s += *reinterpret_cast<const float*>(smemb + GRPB + ((w * 4 + a) * 96 + c) * 4);
            *reinterpret_cast<float*>(smemb + GRB + (a * 96 + c) * 4) = s * inv;
        }
    }

    __syncthreads();   // barrier 4

    // ---- phase 3: D[m][k] = sum_a gr[a][m]*gr[a][k], k<8 ----
    {
        const float* gr = reinterpret_cast<const float*>(smemb + GRB);
        const size_t base = (size_t)bid * 768;
        #pragma unroll
        for (int rep = 0; rep < 4; ++rep) {
            const int o  = tid + rep * 192;
            const int mm = o >> 3;
            const int kk = o & 7;
            float a0 = 0.f;
            #pragma unroll
            for (int a = 0; a < 4; ++a)
                a0 = fmaf(gr[a * 96 + mm], gr[a * 96 + kk], a0);
            out[base + o] = a0;
        }
    }
}

extern "C" void kernel_launch(void* const* d_in, const int* in_sizes, int n_in,
                              void* d_out, int out_size, void* d_ws, size_t ws_size,
                              hipStream_t stream) {
    const float* coord = (const float*)d_in[0];
    const float* davg  = (const float*)d_in[1];
    const float* dstd  = (const float*)d_in[2];
    const float* W1    = (const float*)d_in[3];
    const float* b1    = (const float*)d_in[4];
    const float* W2    = (const float*)d_in[5];
    const float* b2    = (const float*)d_in[6];
    const float* W3    = (const float*)d_in[7];
    const float* b3    = (const float*)d_in[8];
    const int*   atype = (const int*)d_in[9];
    const int*   nlist = (const int*)d_in[10];
    float* out = (float*)d_out;

    descrpt_sea_kernel<<<dim3(NFRAME * NATOMS), dim3(192), 0, stream>>>(
        coord, davg, dstd, W1, b1, W2, b2, W3, b3, atype, nlist, out);
}

// Round 6
// 114.384 us; speedup vs baseline: 4.3106x; 1.4970x over previous
//
#include <hip/hip_runtime.h>

#define NFRAME 2
#define NATOMS 4096
#define NNEI 138
#define SEL0 46
#define N1 24
#define N2 48
#define N3 96

// ---- workspace layout (BYTE offsets) ----
#define WS_W2F 0        // [2 seg][3 nt][64 lane][16B] bf16 B-frags = 6144 B
#define WS_W3F 8192     // [2 seg][6 nt][2 ks][64 lane][16B] bf16 B-frags = 24576 B

// ---- LDS layout (BYTE offsets) ----
#define X2B 0           // 144 rows x 96 B bf16 x2
#define D4B 13824       // 144 rows x 16 B f32x4 d
#define H1B 16128       // 144 rows x 48 B bf16 h1 (+16 B phantom pad)
#define W3FB 16128      // alias over H1B after barrier2: 24576 B frag-major W3
#define GRPB 0          // alias over X2B after barrier4: 3w x 4a x 96 f32 = 4608
#define GRB 4608        // 4 x 96 f32 = 1536
#define SMEM_BYTES 40704 // -> 4 blocks/CU (162816 <= 163840)

using short8 = __attribute__((ext_vector_type(8))) short;
using f32x4  = __attribute__((ext_vector_type(4))) float;

__device__ __forceinline__ float fexp2(float x) {
#if __has_builtin(__builtin_amdgcn_exp2f)
    return __builtin_amdgcn_exp2f(x);
#else
    return exp2f(x);
#endif
}
__device__ __forceinline__ float frcp(float x) {
#if __has_builtin(__builtin_amdgcn_rcpf)
    return __builtin_amdgcn_rcpf(x);
#else
    return 1.0f / x;
#endif
}
// tanh(x) = 1 - 2/(exp(2x)+1); saturates for |x| large
__device__ __forceinline__ float fast_tanh(float x) {
    float e = fexp2(x * 2.8853900817779268f);
    return 1.0f - 2.0f * frcp(e + 1.0f);
}
// RNE f32 -> bf16 bits
__device__ __forceinline__ unsigned int f2bf(float f) {
    unsigned int u = __float_as_uint(f);
    return (u + 0x7fffu + ((u >> 16) & 1u)) >> 16;
}
__device__ __forceinline__ float bf2f(unsigned int b) {
    return __uint_as_float(b << 16);
}

// ---- pre-kernel: pack W2/W3 into bf16 fragment-major B-operand layouts ----
__global__ void prep_kernel(const float* __restrict__ W2,
                            const float* __restrict__ W3,
                            unsigned char* __restrict__ ws)
{
    const int c = blockIdx.x * 256 + threadIdx.x;   // 16B-chunk id
    unsigned short v[8];
    if (c < 384) {                                  // W2 frags
        const int lane = c & 63, fi = c >> 6;       // fi 0..5
        const int seg = fi / 3, nt = fi % 3;
        const int cl = lane & 15, grp = lane >> 4;
        const int col = nt * 16 + cl;
        #pragma unroll
        for (int j = 0; j < 8; ++j) {
            const int k = grp * 8 + j;
            const float fv = (k < N1) ? W2[(seg * N1 + k) * N2 + col] : 0.0f;
            v[j] = (unsigned short)f2bf(fv);
        }
        uint4 q;
        q.x = (unsigned)v[0] | ((unsigned)v[1] << 16);
        q.y = (unsigned)v[2] | ((unsigned)v[3] << 16);
        q.z = (unsigned)v[4] | ((unsigned)v[5] << 16);
        q.w = (unsigned)v[6] | ((unsigned)v[7] << 16);
        *reinterpret_cast<uint4*>(ws + WS_W2F + c * 16) = q;
    } else if (c >= 512 && c < 2048) {              // W3 frags
        const int cc = c - 512;
        const int lane = cc & 63, fi = cc >> 6;     // fi 0..23
        const int seg = fi / 12, r = fi % 12, nt = r >> 1, ks = r & 1;
        const int cl = lane & 15, grp = lane >> 4;
        const int col = nt * 16 + cl;
        #pragma unroll
        for (int j = 0; j < 8; ++j) {
            const int k = ks * 32 + grp * 8 + j;
            const float fv = (k < N2) ? W3[(seg * N2 + k) * N3 + col] : 0.0f;
            v[j] = (unsigned short)f2bf(fv);
        }
        uint4 q;
        q.x = (unsigned)v[0] | ((unsigned)v[1] << 16);
        q.y = (unsigned)v[2] | ((unsigned)v[3] << 16);
        q.z = (unsigned)v[4] | ((unsigned)v[5] << 16);
        q.w = (unsigned)v[6] | ((unsigned)v[7] << 16);
        *reinterpret_cast<uint4*>(ws + WS_W3F + cc * 16) = q;
    }
}

__global__ __launch_bounds__(192) __attribute__((amdgpu_waves_per_eu(3)))
void descrpt_sea_kernel(
    const float* __restrict__ coord,
    const float* __restrict__ davg,
    const float* __restrict__ dstd,
    const float* __restrict__ W1, const float* __restrict__ b1,
    const float* __restrict__ W2, const float* __restrict__ b2,
    const float* __restrict__ W3, const float* __restrict__ b3,
    const int* __restrict__ atype, const int* __restrict__ nlist,
    const unsigned char* __restrict__ ws,
    float* __restrict__ out)
{
    __shared__ float smemf[SMEM_BYTES / 4];
    unsigned char* smemb = reinterpret_cast<unsigned char*>(smemf);

    const int bid  = blockIdx.x;          // f*NATOMS + n
    const int f    = bid >> 12;
    const int tid  = threadIdx.x;
    const int wid  = tid >> 6;
    const int lane = tid & 63;
    const int cl   = lane & 15;
    const int grp  = lane >> 4;

    // lane -> neighbor; padded rows: seg0 -> 0..45 (pad 46,47), seg1 -> 48..139 (pad 140..143)
    int i;
    bool active;
    if (wid == 0)      { i = lane;             active = (lane < SEL0); }
    else if (wid == 1) { i = SEL0 + lane;      active = true; }
    else               { i = SEL0 + 64 + lane; active = (i < NNEI); }
    const int tseg = __builtin_amdgcn_readfirstlane((wid == 0) ? 0 : 1);
    const int prow = (i < SEL0) ? i : (i + 2);

    // ---- early: W2 B-frags straight from ws (L2-resident), b2/b3 per-lane ----
    short8 w2f[3];
    #pragma unroll
    for (int nt = 0; nt < 3; ++nt)
        w2f[nt] = *reinterpret_cast<const short8*>(ws + WS_W2F + (tseg * 3 + nt) * 1024 + lane * 16);

    const float* b2p = b2 + tseg * N2;
    const float* b3p = b3 + tseg * N3;
    float b2v[3], b3v[6];
    #pragma unroll
    for (int nt = 0; nt < 3; ++nt) b2v[nt] = b2p[nt * 16 + cl];
    #pragma unroll
    for (int nt = 0; nt < 6; ++nt) b3v[nt] = b3p[nt * 16 + cl];

    const float cx = coord[bid * 3 + 0];
    const float cy = coord[bid * 3 + 1];
    const float cz = coord[bid * 3 + 2];
    const int at = atype[bid];

    const float* W1p = W1 + tseg * N1;
    const float* b1p = b1 + tseg * N1;

    // ---- zero pads: h1 rows {46,47,140..143} + 16B phantom, d4 same rows ----
    if (tid < 76) {
        if (tid < 72) {
            const int ri = tid / 12;
            const int row = (ri < 2) ? (46 + ri) : (138 + ri);
            *reinterpret_cast<unsigned int*>(smemb + H1B + row * 48 + (tid % 12) * 4) = 0u;
        } else {
            *reinterpret_cast<unsigned int*>(smemb + H1B + 144 * 48 + (tid - 72) * 4) = 0u;
        }
    }
    if (tid < 24) {
        const int ri = tid / 4;
        const int row = (ri < 2) ? (46 + ri) : (138 + ri);
        *reinterpret_cast<unsigned int*>(smemb + D4B + row * 16 + (tid % 4) * 4) = 0u;
    }

    // ---- phase 1: environment matrix d + stage B (h1) ----
    if (active) {
        const int nl = nlist[bid * NNEI + i];
        const float* nc = coord + ((size_t)f * NATOMS + (size_t)nl) * 3;
        float dx = nc[0] - cx, dy = nc[1] - cy, dz = nc[2] - cz;
        float rsq = dx * dx + dy * dy + dz * dz;
        float r = sqrtf(fmaxf(rsq, 1e-12f));
        float uu = (r - 0.5f) * (1.0f / 5.5f);
        float vv = uu * uu * uu * (uu * (-6.0f * uu + 15.0f) - 10.0f) + 1.0f;
        float sw = (r < 0.5f) ? 1.0f : ((r < 6.0f) ? vv : 0.0f);
        float rinv = frcp(r);
        float s = sw * rinv;
        float sor = s * rinv;
        const float* avg  = davg + ((size_t)at * NNEI + i) * 4;
        const float* stdp = dstd + ((size_t)at * NNEI + i) * 4;
        f32x4 dv;
        dv.x = (s        - avg[0]) * frcp(stdp[0]);
        dv.y = (sor * dx - avg[1]) * frcp(stdp[1]);
        dv.z = (sor * dy - avg[2]) * frcp(stdp[2]);
        dv.w = (sor * dz - avg[3]) * frcp(stdp[3]);
        *reinterpret_cast<f32x4*>(smemb + D4B + prow * 16) = dv;

        // stage B: h1 = tanh(x*W1 + b1) -> bf16 LDS row (48 B)
        const float x = dv.x;
        #pragma unroll
        for (int c = 0; c < 3; ++c) {
            unsigned int u[4];
            #pragma unroll
            for (int p = 0; p < 4; ++p) {
                const float h0 = fast_tanh(fmaf(x, W1p[c * 8 + p * 2 + 0], b1p[c * 8 + p * 2 + 0]));
                const float h2 = fast_tanh(fmaf(x, W1p[c * 8 + p * 2 + 1], b1p[c * 8 + p * 2 + 1]));
                u[p] = f2bf(h0) | (f2bf(h2) << 16);
            }
            uint4 w; w.x = u[0]; w.y = u[1]; w.z = u[2]; w.w = u[3];
            *reinterpret_cast<uint4*>(smemb + H1B + prow * 48 + c * 16) = w;
        }
    }

    __syncthreads();   // barrier 1: h1, d4 ready

    // ---- stage C: X2 = concat(h1,h1) + tanh(H1 @ W2 + b2) via MFMA ----
    f32x4 accC[3][3];
    #pragma unroll
    for (int mt = 0; mt < 3; ++mt)
        #pragma unroll
        for (int nt = 0; nt < 3; ++nt) {
            f32x4 c0; c0[0] = b2v[nt]; c0[1] = b2v[nt]; c0[2] = b2v[nt]; c0[3] = b2v[nt];
            accC[mt][nt] = c0;
        }
    #pragma unroll
    for (int mt = 0; mt < 3; ++mt) {
        const int row = (wid * 3 + mt) * 16 + cl;
        // grp=3 reads k=24..31: overruns into next row's h1 (finite); W2 frag k>=24 is 0
        const short8 a = *reinterpret_cast<const short8*>(smemb + H1B + row * 48 + grp * 16);
        #pragma unroll
        for (int nt = 0; nt < 3; ++nt)
            accC[mt][nt] = __builtin_amdgcn_mfma_f32_16x16x32_bf16(a, w2f[nt], accC[mt][nt], 0, 0, 0);
    }
    // epilogue C: x2 = h1[jm] + tanh(acc); write X2 bf16
    #pragma unroll
    for (int mt = 0; mt < 3; ++mt) {
        #pragma unroll
        for (int q = 0; q < 4; ++q) {
            const int r = (wid * 3 + mt) * 16 + grp * 4 + q;
            #pragma unroll
            for (int nt = 0; nt < 3; ++nt) {
                int jm;
                if (nt == 0)      jm = cl;
                else if (nt == 1) jm = (cl < 8) ? (16 + cl) : (cl - 8);
                else              jm = 8 + cl;
                const unsigned short hu =
                    *reinterpret_cast<const unsigned short*>(smemb + H1B + r * 48 + 2 * jm);
                const float x2v = bf2f((unsigned int)hu) + fast_tanh(accC[mt][nt][q]);
                *reinterpret_cast<unsigned short*>(smemb + X2B + r * 96 + 2 * (nt * 16 + cl)) =
                    (unsigned short)f2bf(x2v);
            }
        }
    }

    __syncthreads();   // barrier 2: X2 complete, H1 dead -> W3F alias safe

    // ---- stage W3 frags into LDS (linear, zero-VALU, conflict-free) ----
    #pragma unroll
    for (int it = 0; it < 8; ++it) {
        const int off = it * 3072 + tid * 16;
        __builtin_amdgcn_global_load_lds(
            (const __attribute__((address_space(1))) unsigned int*)(ws + WS_W3F + off),
            (__attribute__((address_space(3))) unsigned int*)(smemb + W3FB + off),
            16, 0, 0);
    }
    asm volatile("s_waitcnt vmcnt(0)");
    __syncthreads();   // barrier 3: W3F ready

    // ---- stage D: G-matmul via MFMA; C init = b3 ----
    f32x4 acc[3][6];
    #pragma unroll
    for (int mt = 0; mt < 3; ++mt)
        #pragma unroll
        for (int nt = 0; nt < 6; ++nt) {
            f32x4 c0; c0[0] = b3v[nt]; c0[1] = b3v[nt]; c0[2] = b3v[nt]; c0[3] = b3v[nt];
            acc[mt][nt] = c0;
        }
    const short8 zero8 = (short8){0,0,0,0,0,0,0,0};
    short8 a0[3], a1[3];
    #pragma unroll
    for (int mt = 0; mt < 3; ++mt) {
        const int row = (wid * 3 + mt) * 16 + cl;
        a0[mt] = *reinterpret_cast<const short8*>(smemb + X2B + row * 96 + grp * 16);
        short8 t = *reinterpret_cast<const short8*>(smemb + X2B + row * 96 + 64 + (grp & 1) * 16);
        a1[mt] = (grp < 2) ? t : zero8;   // zero k=48..63
    }
    #pragma unroll
    for (int nt = 0; nt < 6; ++nt) {
        const int fb = W3FB + ((tseg * 6 + nt) * 2) * 1024 + lane * 16;
        const short8 bk0 = *reinterpret_cast<const short8*>(smemb + fb);
        const short8 bk1 = *reinterpret_cast<const short8*>(smemb + fb + 1024);
        #pragma unroll
        for (int mt = 0; mt < 3; ++mt) {
            acc[mt][nt] = __builtin_amdgcn_mfma_f32_16x16x32_bf16(a0[mt], bk0, acc[mt][nt], 0, 0, 0);
            acc[mt][nt] = __builtin_amdgcn_mfma_f32_16x16x32_bf16(a1[mt], bk1, acc[mt][nt], 0, 0, 0);
        }
    }

    // ---- epilogue D: G = x2c + tanh(acc); gsum[a][nt] += d[row][a]*G ----
    float gsum[4][6];
    #pragma unroll
    for (int a = 0; a < 4; ++a)
        #pragma unroll
        for (int nt = 0; nt < 6; ++nt) gsum[a][nt] = 0.f;

    #pragma unroll
    for (int mt = 0; mt < 3; ++mt) {
        f32x4 dv[4];
        float x2v[4][3];
        #pragma unroll
        for (int q = 0; q < 4; ++q) {
            const int r = (wid * 3 + mt) * 16 + grp * 4 + q;
            dv[q] = *reinterpret_cast<const f32x4*>(smemb + D4B + r * 16);
            #pragma unroll
            for (int c0 = 0; c0 < 3; ++c0) {
                const unsigned short u =
                    *reinterpret_cast<const unsigned short*>(smemb + X2B + r * 96 + 2 * (c0 * 16 + cl));
                x2v[q][c0] = bf2f((unsigned int)u);
            }
        }
        #pragma unroll
        for (int nt = 0; nt < 6; ++nt) {
            const int c0 = (nt < 3) ? nt : (nt - 3);
            #pragma unroll
            for (int q = 0; q < 4; ++q) {
                const float g = x2v[q][c0] + fast_tanh(acc[mt][nt][q]);
                gsum[0][nt] = fmaf(dv[q].x, g, gsum[0][nt]);
                gsum[1][nt] = fmaf(dv[q].y, g, gsum[1][nt]);
                gsum[2][nt] = fmaf(dv[q].z, g, gsum[2][nt]);
                gsum[3][nt] = fmaf(dv[q].w, g, gsum[3][nt]);
            }
        }
    }

    // ---- cross-lane reduce (lane^16, lane^32) ----
    float red[24];
    #pragma unroll
    for (int a = 0; a < 4; ++a) {
        #pragma unroll
        for (int nt = 0; nt < 6; ++nt) {
            float v = gsum[a][nt];
            v += __shfl_xor(v, 16, 64);
            v += __shfl_xor(v, 32, 64);
            red[a * 6 + nt] = v;
        }
    }

    __syncthreads();   // barrier 4: X2/d4 reads done -> GRPB alias safe

    if (lane < 16) {
        #pragma unroll
        for (int a = 0; a < 4; ++a)
            #pragma unroll
            for (int nt = 0; nt < 6; ++nt)
                *reinterpret_cast<float*>(smemb + GRPB +
                    (((wid * 4 + a) * 96) + nt * 16 + lane) * 4) = red[a * 6 + nt];
    }

    __syncthreads();   // barrier 5

    // ---- final gr = sum over 3 waves, /NNEI ----
    {
        const float inv = 1.0f / (float)NNEI;
        #pragma unroll
        for (int rep = 0; rep < 2; ++rep) {
            const int id = tid + rep * 192;
            const int a = id / 96;
            const int c = id - a * 96;
            float s = 0.f;
            #pragma unroll
            for (int w = 0; w < 3; ++w)
                s += *reinterpret_cast<const float*>(smemb + GRPB + ((w * 4 + a) * 96 + c) * 4);
            *reinterpret_cast<float*>(smemb + GRB + (a * 96 + c) * 4) = s * inv;
        }
    }

    __syncthreads();   // barrier 6

    // ---- phase 3: D[m][k] = sum_a gr[a][m]*gr[a][k], k<8 ----
    {
        const float* gr = reinterpret_cast<const float*>(smemb + GRB);
        const size_t base = (size_t)bid * 768;
        #pragma unroll
        for (int rep = 0; rep < 4; ++rep) {
            const int o  = tid + rep * 192;
            const int mm = o >> 3;
            const int kk = o & 7;
            float a0v = 0.f;
            #pragma unroll
            for (int a = 0; a < 4; ++a)
                a0v = fmaf(gr[a * 96 + mm], gr[a * 96 + kk], a0v);
            out[base + o] = a0v;
        }
    }
}

extern "C" void kernel_launch(void* const* d_in, const int* in_sizes, int n_in,
                              void* d_out, int out_size, void* d_ws, size_t ws_size,
                              hipStream_t stream) {
    const float* coord = (const float*)d_in[0];
    const float* davg  = (const float*)d_in[1];
    const float* dstd  = (const float*)d_in[2];
    const float* W1    = (const float*)d_in[3];
    const float* b1    = (const float*)d_in[4];
    const float* W2    = (const float*)d_in[5];
    const float* b2    = (const float*)d_in[6];
    const float* W3    = (const float*)d_in[7];
    const float* b3    = (const float*)d_in[8];
    const int*   atype = (const int*)d_in[9];
    const int*   nlist = (const int*)d_in[10];
    float* out = (float*)d_out;
    unsigned char* ws = (unsigned char*)d_ws;

    prep_kernel<<<dim3(8), dim3(256), 0, stream>>>(W2, W3, ws);
    descrpt_sea_kernel<<<dim3(NFRAME * NATOMS), dim3(192), 0, stream>>>(
        coord, davg, dstd, W1, b1, W2, b2, W3, b3, atype, nlist, ws, out);
}

// Round 7
// 111.245 us; speedup vs baseline: 4.4322x; 1.0282x over previous
//
#include <hip/hip_runtime.h>

#define NFRAME 2
#define NATOMS 4096
#define NNEI 138
#define SEL0 46
#define N1 24
#define N2 48
#define N3 96

// ---- workspace layout (BYTE offsets) ----
#define WS_W2F 0        // [2 seg][3 nt][64 lane][16B] bf16 B-frags = 6144 B
#define WS_W3F 8192     // [2 seg][6 nt][2 ks][64 lane][16B] bf16 B-frags = 24576 B

// ---- LDS layout (BYTE offsets) ----
// strides chosen so gcd(stride/4, 32) == 2 -> worst 2-way bank aliasing (free)
#define X2B 0            // 144 rows x 104 B (96 B bf16 x2 + 8 B pad)
#define X2S 104
#define D4B 14976        // 144 rows x 16 B f32x4 d
#define H1B 17280        // 145 rows x 56 B (48 B bf16 h1 + 8 B zero pad; row 144 phantom)
#define H1S 56
#define GRPB 0           // alias over X2B after final barrier: 3w x 4a x 96 f32 = 4608
#define GRB 4608         // 4 x 96 f32 = 1536
#define SMEM_BYTES 25408

using short8 = __attribute__((ext_vector_type(8))) short;
using f32x4  = __attribute__((ext_vector_type(4))) float;

__device__ __forceinline__ float fexp2(float x) {
#if __has_builtin(__builtin_amdgcn_exp2f)
    return __builtin_amdgcn_exp2f(x);
#else
    return exp2f(x);
#endif
}
__device__ __forceinline__ float frcp(float x) {
#if __has_builtin(__builtin_amdgcn_rcpf)
    return __builtin_amdgcn_rcpf(x);
#else
    return 1.0f / x;
#endif
}
// tanh(x) = 1 - 2/(exp(2x)+1); saturates for |x| large
__device__ __forceinline__ float fast_tanh(float x) {
    float e = fexp2(x * 2.8853900817779268f);
    return 1.0f - 2.0f * frcp(e + 1.0f);
}
// RNE f32 -> bf16 bits (cold path / prep kernel)
__device__ __forceinline__ unsigned int f2bf(float f) {
    unsigned int u = __float_as_uint(f);
    return (u + 0x7fffu + ((u >> 16) & 1u)) >> 16;
}
__device__ __forceinline__ float bf2f(unsigned int b) {
    return __uint_as_float(b << 16);
}
// hot path: 1-instr packed convert, lo = bf16(a), hi = bf16(b)
__device__ __forceinline__ unsigned int cvt_pk_bf16(float a, float b) {
    unsigned int r;
    asm("v_cvt_pk_bf16_f32 %0, %1, %2" : "=v"(r) : "v"(a), "v"(b));
    return r;
}

// ---- pre-kernel: pack W2/W3 into bf16 fragment-major B-operand layouts ----
__global__ void prep_kernel(const float* __restrict__ W2,
                            const float* __restrict__ W3,
                            unsigned char* __restrict__ ws)
{
    const int c = blockIdx.x * 256 + threadIdx.x;   // 16B-chunk id
    unsigned short v[8];
    if (c < 384) {                                  // W2 frags
        const int lane = c & 63, fi = c >> 6;       // fi 0..5
        const int seg = fi / 3, nt = fi % 3;
        const int cl = lane & 15, grp = lane >> 4;
        const int col = nt * 16 + cl;
        #pragma unroll
        for (int j = 0; j < 8; ++j) {
            const int k = grp * 8 + j;
            const float fv = (k < N1) ? W2[(seg * N1 + k) * N2 + col] : 0.0f;
            v[j] = (unsigned short)f2bf(fv);
        }
        uint4 q;
        q.x = (unsigned)v[0] | ((unsigned)v[1] << 16);
        q.y = (unsigned)v[2] | ((unsigned)v[3] << 16);
        q.z = (unsigned)v[4] | ((unsigned)v[5] << 16);
        q.w = (unsigned)v[6] | ((unsigned)v[7] << 16);
        *reinterpret_cast<uint4*>(ws + WS_W2F + c * 16) = q;
    } else if (c >= 512 && c < 2048) {              // W3 frags
        const int cc = c - 512;
        const int lane = cc & 63, fi = cc >> 6;     // fi 0..23
        const int seg = fi / 12, r = fi % 12, nt = r >> 1, ks = r & 1;
        const int cl = lane & 15, grp = lane >> 4;
        const int col = nt * 16 + cl;
        #pragma unroll
        for (int j = 0; j < 8; ++j) {
            const int k = ks * 32 + grp * 8 + j;
            const float fv = (k < N2) ? W3[(seg * N2 + k) * N3 + col] : 0.0f;
            v[j] = (unsigned short)f2bf(fv);
        }
        uint4 q;
        q.x = (unsigned)v[0] | ((unsigned)v[1] << 16);
        q.y = (unsigned)v[2] | ((unsigned)v[3] << 16);
        q.z = (unsigned)v[4] | ((unsigned)v[5] << 16);
        q.w = (unsigned)v[6] | ((unsigned)v[7] << 16);
        *reinterpret_cast<uint4*>(ws + WS_W3F + cc * 16) = q;
    }
}

__global__ __launch_bounds__(192) __attribute__((amdgpu_waves_per_eu(4)))
void descrpt_sea_kernel(
    const float* __restrict__ coord,
    const float* __restrict__ davg,
    const float* __restrict__ dstd,
    const float* __restrict__ W1, const float* __restrict__ b1,
    const float* __restrict__ W2, const float* __restrict__ b2,
    const float* __restrict__ W3, const float* __restrict__ b3,
    const int* __restrict__ atype, const int* __restrict__ nlist,
    const unsigned char* __restrict__ ws,
    float* __restrict__ out)
{
    __shared__ float smemf[SMEM_BYTES / 4];
    unsigned char* smemb = reinterpret_cast<unsigned char*>(smemf);

    const int bid  = blockIdx.x;          // f*NATOMS + n
    const int f    = bid >> 12;
    const int tid  = threadIdx.x;
    const int wid  = tid >> 6;
    const int lane = tid & 63;
    const int cl   = lane & 15;
    const int grp  = lane >> 4;

    // lane -> neighbor; padded rows: seg0 -> 0..45 (pad 46,47), seg1 -> 48..139 (pad 140..143)
    int i;
    bool active;
    if (wid == 0)      { i = lane;             active = (lane < SEL0); }
    else if (wid == 1) { i = SEL0 + lane;      active = true; }
    else               { i = SEL0 + 64 + lane; active = (i < NNEI); }
    const int tseg = __builtin_amdgcn_readfirstlane((wid == 0) ? 0 : 1);
    const int prow = (i < SEL0) ? i : (i + 2);

    // ---- W2 B-frags straight from ws (L2-resident), b2/b3 per-lane ----
    short8 w2f[3];
    #pragma unroll
    for (int nt = 0; nt < 3; ++nt)
        w2f[nt] = *reinterpret_cast<const short8*>(ws + WS_W2F + (tseg * 3 + nt) * 1024 + lane * 16);

    const float* b2p = b2 + tseg * N2;
    const float* b3p = b3 + tseg * N3;
    float b2v[3], b3v[6];
    #pragma unroll
    for (int nt = 0; nt < 3; ++nt) b2v[nt] = b2p[nt * 16 + cl];
    #pragma unroll
    for (int nt = 0; nt < 6; ++nt) b3v[nt] = b3p[nt * 16 + cl];

    const float cx = coord[bid * 3 + 0];
    const float cy = coord[bid * 3 + 1];
    const float cz = coord[bid * 3 + 2];
    const int at = atype[bid];

    const float* W1p = W1 + tseg * N1;
    const float* b1p = b1 + tseg * N1;

    // ---- zero fills ----
    // 8B pad tail of every h1 row (grp3 A-frag reads k=24..27 from here; must be finite)
    if (tid < 144)
        *reinterpret_cast<uint2*>(smemb + H1B + tid * H1S + 48) = (uint2){0u, 0u};
    // phantom row 144 (row 143 grp3 overrun)
    if (tid < 14)
        *reinterpret_cast<unsigned int*>(smemb + H1B + 144 * H1S + tid * 4) = 0u;
    // pad-atom h1 rows {46,47,140..143} fully zero
    if (tid < 84) {
        const int ri = tid / 14;
        const int row = (ri < 2) ? (46 + ri) : (138 + ri);
        *reinterpret_cast<unsigned int*>(smemb + H1B + row * H1S + (tid % 14) * 4) = 0u;
    }
    // pad-atom d rows zero
    if (tid < 24) {
        const int ri = tid / 4;
        const int row = (ri < 2) ? (46 + ri) : (138 + ri);
        *reinterpret_cast<unsigned int*>(smemb + D4B + row * 16 + (tid % 4) * 4) = 0u;
    }

    // ---- phase 1: environment matrix d + stage B (h1) ----
    if (active) {
        const int nl = nlist[bid * NNEI + i];
        const float* nc = coord + ((size_t)f * NATOMS + (size_t)nl) * 3;
        float dx = nc[0] - cx, dy = nc[1] - cy, dz = nc[2] - cz;
        float rsq = dx * dx + dy * dy + dz * dz;
        float r = sqrtf(fmaxf(rsq, 1e-12f));
        float uu = (r - 0.5f) * (1.0f / 5.5f);
        float vv = uu * uu * uu * (uu * (-6.0f * uu + 15.0f) - 10.0f) + 1.0f;
        float sw = (r < 0.5f) ? 1.0f : ((r < 6.0f) ? vv : 0.0f);
        float rinv = frcp(r);
        float s = sw * rinv;
        float sor = s * rinv;
        const float* avg  = davg + ((size_t)at * NNEI + i) * 4;
        const float* stdp = dstd + ((size_t)at * NNEI + i) * 4;
        f32x4 dv;
        dv.x = (s        - avg[0]) * frcp(stdp[0]);
        dv.y = (sor * dx - avg[1]) * frcp(stdp[1]);
        dv.z = (sor * dy - avg[2]) * frcp(stdp[2]);
        dv.w = (sor * dz - avg[3]) * frcp(stdp[3]);
        *reinterpret_cast<f32x4*>(smemb + D4B + prow * 16) = dv;

        // stage B: h1 = tanh(x*W1 + b1) -> bf16 LDS row
        const float x = dv.x;
        #pragma unroll
        for (int c = 0; c < 3; ++c) {
            unsigned int u[4];
            #pragma unroll
            for (int p = 0; p < 4; ++p) {
                const float h0 = fast_tanh(fmaf(x, W1p[c * 8 + p * 2 + 0], b1p[c * 8 + p * 2 + 0]));
                const float h2 = fast_tanh(fmaf(x, W1p[c * 8 + p * 2 + 1], b1p[c * 8 + p * 2 + 1]));
                u[p] = cvt_pk_bf16(h0, h2);
            }
            uint4 w; w.x = u[0]; w.y = u[1]; w.z = u[2]; w.w = u[3];
            *reinterpret_cast<uint4*>(smemb + H1B + prow * H1S + c * 16) = w;
        }
    }

    __syncthreads();   // barrier 1: h1, d4 ready

    // ---- stage C: X2 = concat(h1,h1) + tanh(H1 @ W2 + b2) via MFMA ----
    f32x4 accC[3][3];
    #pragma unroll
    for (int mt = 0; mt < 3; ++mt)
        #pragma unroll
        for (int nt = 0; nt < 3; ++nt) {
            f32x4 c0; c0[0] = b2v[nt]; c0[1] = b2v[nt]; c0[2] = b2v[nt]; c0[3] = b2v[nt];
            accC[mt][nt] = c0;
        }
    #pragma unroll
    for (int mt = 0; mt < 3; ++mt) {
        const int row = (wid * 3 + mt) * 16 + cl;
        // grp3 reads k=24..31 -> zeroed pad + next row head; W2 frag k>=24 is 0
        const short8 a = *reinterpret_cast<const short8*>(smemb + H1B + row * H1S + grp * 16);
        #pragma unroll
        for (int nt = 0; nt < 3; ++nt)
            accC[mt][nt] = __builtin_amdgcn_mfma_f32_16x16x32_bf16(a, w2f[nt], accC[mt][nt], 0, 0, 0);
    }
    // epilogue C: x2 = h1[jm] + tanh(acc); write X2 bf16
    #pragma unroll
    for (int mt = 0; mt < 3; ++mt) {
        #pragma unroll
        for (int q = 0; q < 4; ++q) {
            const int r = (wid * 3 + mt) * 16 + grp * 4 + q;
            #pragma unroll
            for (int nt = 0; nt < 3; ++nt) {
                int jm;
                if (nt == 0)      jm = cl;
                else if (nt == 1) jm = (cl < 8) ? (16 + cl) : (cl - 8);
                else              jm = 8 + cl;
                const unsigned short hu =
                    *reinterpret_cast<const unsigned short*>(smemb + H1B + r * H1S + 2 * jm);
                const float x2v = bf2f((unsigned int)hu) + fast_tanh(accC[mt][nt][q]);
                *reinterpret_cast<unsigned short*>(smemb + X2B + r * X2S + 2 * (nt * 16 + cl)) =
                    (unsigned short)cvt_pk_bf16(x2v, x2v);
            }
        }
    }

    __syncthreads();   // barrier 2: X2 complete

    // ---- stage D: G-matmul via MFMA, two 3-nt passes (halves acc regs) ----
    const short8 zero8 = (short8){0,0,0,0,0,0,0,0};
    short8 a0[3], a1[3];
    #pragma unroll
    for (int mt = 0; mt < 3; ++mt) {
        const int row = (wid * 3 + mt) * 16 + cl;
        a0[mt] = *reinterpret_cast<const short8*>(smemb + X2B + row * X2S + grp * 16);
        short8 t = *reinterpret_cast<const short8*>(smemb + X2B + row * X2S + 64 + (grp & 1) * 16);
        a1[mt] = (grp < 2) ? t : zero8;   // zero k=48..63
    }

    const unsigned char* w3p = ws + WS_W3F + tseg * 12288 + lane * 16;
    float red[24];

    #pragma unroll
    for (int pass = 0; pass < 2; ++pass) {
        f32x4 acc[3][3];
        #pragma unroll
        for (int mt = 0; mt < 3; ++mt)
            #pragma unroll
            for (int ntl = 0; ntl < 3; ++ntl) {
                const float b = b3v[pass * 3 + ntl];
                f32x4 c0; c0[0] = b; c0[1] = b; c0[2] = b; c0[3] = b;
                acc[mt][ntl] = c0;
            }
        // double-buffered direct-global B-frag loads (L2-resident)
        short8 nb0 = *reinterpret_cast<const short8*>(w3p + (pass * 3) * 2048);
        short8 nb1 = *reinterpret_cast<const short8*>(w3p + (pass * 3) * 2048 + 1024);
        #pragma unroll
        for (int ntl = 0; ntl < 3; ++ntl) {
            const short8 bk0 = nb0, bk1 = nb1;
            if (ntl < 2) {
                nb0 = *reinterpret_cast<const short8*>(w3p + (pass * 3 + ntl + 1) * 2048);
                nb1 = *reinterpret_cast<const short8*>(w3p + (pass * 3 + ntl + 1) * 2048 + 1024);
            }
            #pragma unroll
            for (int mt = 0; mt < 3; ++mt) {
                acc[mt][ntl] = __builtin_amdgcn_mfma_f32_16x16x32_bf16(a0[mt], bk0, acc[mt][ntl], 0, 0, 0);
                acc[mt][ntl] = __builtin_amdgcn_mfma_f32_16x16x32_bf16(a1[mt], bk1, acc[mt][ntl], 0, 0, 0);
            }
        }

        // epilogue: G = x2c + tanh(acc); gsum[a][ntl] += d[row][a]*G
        float gsum[4][3];
        #pragma unroll
        for (int a = 0; a < 4; ++a)
            #pragma unroll
            for (int ntl = 0; ntl < 3; ++ntl) gsum[a][ntl] = 0.f;

        #pragma unroll
        for (int mt = 0; mt < 3; ++mt) {
            #pragma unroll
            for (int q = 0; q < 4; ++q) {
                const int r = (wid * 3 + mt) * 16 + grp * 4 + q;
                const f32x4 dv = *reinterpret_cast<const f32x4*>(smemb + D4B + r * 16);
                #pragma unroll
                for (int ntl = 0; ntl < 3; ++ntl) {
                    const unsigned short u =
                        *reinterpret_cast<const unsigned short*>(smemb + X2B + r * X2S + 2 * (ntl * 16 + cl));
                    const float g = bf2f((unsigned int)u) + fast_tanh(acc[mt][ntl][q]);
                    gsum[0][ntl] = fmaf(dv.x, g, gsum[0][ntl]);
                    gsum[1][ntl] = fmaf(dv.y, g, gsum[1][ntl]);
                    gsum[2][ntl] = fmaf(dv.z, g, gsum[2][ntl]);
                    gsum[3][ntl] = fmaf(dv.w, g, gsum[3][ntl]);
                }
            }
        }
        // cross-lane reduce (lane^16, lane^32), hold in regs until alias barrier
        #pragma unroll
        for (int a = 0; a < 4; ++a)
            #pragma unroll
            for (int ntl = 0; ntl < 3; ++ntl) {
                float v = gsum[a][ntl];
                v += __shfl_xor(v, 16, 64);
                v += __shfl_xor(v, 32, 64);
                red[a * 6 + pass * 3 + ntl] = v;
            }
    }

    __syncthreads();   // barrier 3: X2/d4 reads done -> GRPB alias safe

    if (lane < 16) {
        #pragma unroll
        for (int a = 0; a < 4; ++a)
            #pragma unroll
            for (int nt = 0; nt < 6; ++nt)
                *reinterpret_cast<float*>(smemb + GRPB +
                    (((wid * 4 + a) * 96) + nt * 16 + lane) * 4) = red[a * 6 + nt];
    }

    __syncthreads();   // barrier 4

    // ---- final gr = sum over 3 waves, /NNEI ----
    {
        const float inv = 1.0f / (float)NNEI;
        #pragma unroll
        for (int rep = 0; rep < 2; ++rep) {
            const int id = tid + rep * 192;
            const int a = id / 96;
            const int c = id - a * 96;
            float s = 0.f;
            #pragma unroll
            for (int w = 0; w < 3; ++w)
                s += *reinterpret_cast<const float*>(smemb + GRPB + ((w * 4 + a) * 96 + c) * 4);
            *reinterpret_cast<float*>(smemb + GRB + (a * 96 + c) * 4) = s * inv;
        }
    }

    __syncthreads();   // barrier 5

    // ---- phase 3: D[m][k] = sum_a gr[a][m]*gr[a][k], k<8 ----
    {
        const float* gr = reinterpret_cast<const float*>(smemb + GRB);
        const size_t base = (size_t)bid * 768;
        #pragma unroll
        for (int rep = 0; rep < 4; ++rep) {
            const int o  = tid + rep * 192;
            const int mm = o >> 3;
            const int kk = o & 7;
            float a0v = 0.f;
            #pragma unroll
            for (int a = 0; a < 4; ++a)
                a0v = fmaf(gr[a * 96 + mm], gr[a * 96 + kk], a0v);
            out[base + o] = a0v;
        }
    }
}

extern "C" void kernel_launch(void* const* d_in, const int* in_sizes, int n_in,
                              void* d_out, int out_size, void* d_ws, size_t ws_size,
                              hipStream_t stream) {
    const float* coord = (const float*)d_in[0];
    const float* davg  = (const float*)d_in[1];
    const float* dstd  = (const float*)d_in[2];
    const float* W1    = (const float*)d_in[3];
    const float* b1    = (const float*)d_in[4];
    const float* W2    = (const float*)d_in[5];
    const float* b2    = (const float*)d_in[6];
    const float* W3    = (const float*)d_in[7];
    const float* b3    = (const float*)d_in[8];
    const int*   atype = (const int*)d_in[9];
    const int*   nlist = (const int*)d_in[10];
    float* out = (float*)d_out;
    unsigned char* ws = (unsigned char*)d_ws;

    prep_kernel<<<dim3(8), dim3(256), 0, stream>>>(W2, W3, ws);
    descrpt_sea_kernel<<<dim3(NFRAME * NATOMS), dim3(192), 0, stream>>>(
        coord, davg, dstd, W1, b1, W2, b2, W3, b3, atype, nlist, ws, out);
}

// Round 8
// 96.535 us; speedup vs baseline: 5.1077x; 1.1524x over previous
//
#include <hip/hip_runtime.h>

#define NFRAME 2
#define NATOMS 4096
#define NNEI 138
#define SEL0 46
#define N1 24
#define N2 48
#define N3 96

// ---- workspace layout (BYTE offsets) ----
#define WS_W2F 0        // [2 seg][3 nt][64 lane][16B] bf16 W2 B-frags = 6144 B
#define WS_W3F 8192     // [2 seg][6 nt][2 ks][64 lane][16B] bf16 W3 B-frags = 24576 B
#define WS_SF  32768    // [3 ntl][2 ks][64 lane][16B] identity-48 B-frags = 6144 B
#define WS_SF2 38912    // [3 ntl][64 lane][16B] concat-24 B-frags = 3072 B

// ---- LDS layout (BYTE offsets) ----
// GF: G in B-frag layout [6 ntg][5 ks][64 lane][16B] = 30720 B.
//   Aliases X2 (0..14976) + H1 (14976..23096) + spare — both dead after barrier3.
#define GFB 0
#define GFS 5120        // per-ntg stride
#define X2B 0           // 144 rows x 104 B bf16 x2
#define X2S 104
#define H1B 14976       // 145 rows x 56 B bf16 h1 (48 B + 8 B zero pad; row 144 phantom)
#define H1S 56
#define DFB 30720       // d in A-frag layout, compact cl<4: [5 ks][16 slot][16B] = 1280 B
#define GRBB 0          // gr 4x96 f32 = 1536 B, aliases GF ntg0 after barrier5a
#define SMEM_BYTES 32000 // -> 5 blocks/CU (160000 <= 163840)

using short8 = __attribute__((ext_vector_type(8))) short;
using f32x4  = __attribute__((ext_vector_type(4))) float;

__device__ __forceinline__ float fexp2(float x) {
#if __has_builtin(__builtin_amdgcn_exp2f)
    return __builtin_amdgcn_exp2f(x);
#else
    return exp2f(x);
#endif
}
__device__ __forceinline__ float frcp(float x) {
#if __has_builtin(__builtin_amdgcn_rcpf)
    return __builtin_amdgcn_rcpf(x);
#else
    return 1.0f / x;
#endif
}
// tanh(x) = 1 - 2/(exp(2x)+1); saturates for |x| large
__device__ __forceinline__ float fast_tanh(float x) {
    float e = fexp2(x * 2.8853900817779268f);
    return 1.0f - 2.0f * frcp(e + 1.0f);
}
// RNE f32 -> bf16 bits (prep kernel)
__device__ __forceinline__ unsigned int f2bf(float f) {
    unsigned int u = __float_as_uint(f);
    return (u + 0x7fffu + ((u >> 16) & 1u)) >> 16;
}
// hot path: 1-instr packed convert, lo = bf16(a), hi = bf16(b)
__device__ __forceinline__ unsigned int cvt_pk_bf16(float a, float b) {
    unsigned int r;
    asm("v_cvt_pk_bf16_f32 %0, %1, %2" : "=v"(r) : "v"(a), "v"(b));
    return r;
}

// ---- pre-kernel: pack W2/W3/S/S2 into bf16 fragment-major B-operand layouts ----
__global__ void prep_kernel(const float* __restrict__ W2,
                            const float* __restrict__ W3,
                            unsigned char* __restrict__ ws)
{
    const int c = blockIdx.x * 256 + threadIdx.x;   // 16B-chunk id
    const int lane = c & 63;
    const int cl = lane & 15, grp = lane >> 4;
    unsigned short v[8];
    if (c < 384) {                                  // W2 frags
        const int fi = c >> 6;                      // 0..5
        const int seg = fi / 3, nt = fi % 3;
        const int col = nt * 16 + cl;
        #pragma unroll
        for (int j = 0; j < 8; ++j) {
            const int k = grp * 8 + j;
            const float fv = (k < N1) ? W2[(seg * N1 + k) * N2 + col] : 0.0f;
            v[j] = (unsigned short)f2bf(fv);
        }
    } else if (c >= 512 && c < 2048) {              // W3 frags
        const int cc = c - 512;
        const int fi = cc >> 6;                     // 0..23
        const int seg = fi / 12, r = fi % 12, nt = r >> 1, ks = r & 1;
        const int col = nt * 16 + cl;
        #pragma unroll
        for (int j = 0; j < 8; ++j) {
            const int k = ks * 32 + grp * 8 + j;
            const float fv = (k < N2) ? W3[(seg * N2 + k) * N3 + col] : 0.0f;
            v[j] = (unsigned short)f2bf(fv);
        }
    } else if (c >= 2048 && c < 2432) {             // S: identity-48 (x2 skip)
        const int cc = c - 2048;
        const int fi = cc >> 6;                     // 0..5
        const int ntl = fi >> 1, ks = fi & 1;
        const int col = ntl * 16 + cl;
        #pragma unroll
        for (int j = 0; j < 8; ++j) {
            const int k = ks * 32 + grp * 8 + j;
            v[j] = (k == col) ? (unsigned short)0x3F80 : (unsigned short)0;
        }
    } else if (c >= 2432 && c < 2624) {             // S2: concat-24 (h1 skip)
        const int cc = c - 2432;
        const int ntl = cc >> 6;                    // 0..2
        const int col = ntl * 16 + cl;
        const int cm = (col < 24) ? col : (col - 24);
        #pragma unroll
        for (int j = 0; j < 8; ++j) {
            const int k = grp * 8 + j;
            v[j] = (k == cm) ? (unsigned short)0x3F80 : (unsigned short)0;
        }
    } else {
        return;
    }
    uint4 q;
    q.x = (unsigned)v[0] | ((unsigned)v[1] << 16);
    q.y = (unsigned)v[2] | ((unsigned)v[3] << 16);
    q.z = (unsigned)v[4] | ((unsigned)v[5] << 16);
    q.w = (unsigned)v[6] | ((unsigned)v[7] << 16);
    int off;
    if (c < 384)       off = WS_W2F + c * 16;
    else if (c < 2048) off = WS_W3F + (c - 512) * 16;
    else if (c < 2432) off = WS_SF  + (c - 2048) * 16;
    else               off = WS_SF2 + (c - 2432) * 16;
    *reinterpret_cast<uint4*>(ws + off) = q;
}

__global__ __launch_bounds__(192) __attribute__((amdgpu_waves_per_eu(3)))
void descrpt_sea_kernel(
    const float* __restrict__ coord,
    const float* __restrict__ davg,
    const float* __restrict__ dstd,
    const float* __restrict__ W1, const float* __restrict__ b1,
    const float* __restrict__ W2, const float* __restrict__ b2,
    const float* __restrict__ W3, const float* __restrict__ b3,
    const int* __restrict__ atype, const int* __restrict__ nlist,
    const unsigned char* __restrict__ ws,
    float* __restrict__ out)
{
    __shared__ float smemf[SMEM_BYTES / 4];
    unsigned char* smemb = reinterpret_cast<unsigned char*>(smemf);

    const int bid  = blockIdx.x;          // f*NATOMS + n
    const int f    = bid >> 12;
    const int tid  = threadIdx.x;
    const int wid  = tid >> 6;
    const int lane = tid & 63;
    const int cl   = lane & 15;
    const int grp  = lane >> 4;

    // lane -> neighbor; padded rows: seg0 -> 0..45 (pad 46,47), seg1 -> 48..139 (pad 140..143)
    int i;
    bool active;
    if (wid == 0)      { i = lane;             active = (lane < SEL0); }
    else if (wid == 1) { i = SEL0 + lane;      active = true; }
    else               { i = SEL0 + 64 + lane; active = (i < NNEI); }
    const int tseg = __builtin_amdgcn_readfirstlane((wid == 0) ? 0 : 1);
    const int prow = (i < SEL0) ? i : (i + 2);

    // ---- W2/S2 B-frags from ws (L2-resident), b2/b3 per-lane ----
    short8 w2f[3], sf2[3];
    #pragma unroll
    for (int nt = 0; nt < 3; ++nt) {
        w2f[nt] = *reinterpret_cast<const short8*>(ws + WS_W2F + (tseg * 3 + nt) * 1024 + lane * 16);
        sf2[nt] = *reinterpret_cast<const short8*>(ws + WS_SF2 + nt * 1024 + lane * 16);
    }
    const float* b2p = b2 + tseg * N2;
    const float* b3p = b3 + tseg * N3;
    float b2v[3], b3v[6];
    #pragma unroll
    for (int nt = 0; nt < 3; ++nt) b2v[nt] = b2p[nt * 16 + cl];
    #pragma unroll
    for (int nt = 0; nt < 6; ++nt) b3v[nt] = b3p[nt * 16 + cl];

    const float cx = coord[bid * 3 + 0];
    const float cy = coord[bid * 3 + 1];
    const float cz = coord[bid * 3 + 2];
    const int at = atype[bid];

    const float* W1p = W1 + tseg * N1;
    const float* b1p = b1 + tseg * N1;

    // ---- zero fills (all disjoint from producer writes; no barrier needed) ----
    // DF slots with no producer: rows {46,47} u {140..159}, 4 a-slots each
    if (tid < 88) {
        const int t = tid >> 2;                          // 0..21
        const int row = (t < 2) ? (46 + t) : (138 + t);  // 46,47,140..159
        const int a = tid & 3;
        const int byte = DFB + ((row >> 5) << 8) + ((((row >> 3) & 3) * 4 + a) << 4)
                       + ((row & 7) << 1);
        *reinterpret_cast<unsigned short*>(smemb + byte) = 0;
    }
    // h1 row tails (8B at +48) for all 144 rows
    if (tid < 144)
        *reinterpret_cast<uint2*>(smemb + H1B + tid * H1S + 48) = (uint2){0u, 0u};
    // phantom row 144
    if (tid < 14)
        *reinterpret_cast<unsigned int*>(smemb + H1B + 144 * H1S + tid * 4) = 0u;
    // pad-atom h1 rows {46,47,140..143} fully zero (56 B = 14 words each)
    if (tid < 84) {
        const int ri = tid / 14;
        const int row = (ri < 2) ? (46 + ri) : (138 + ri);
        *reinterpret_cast<unsigned int*>(smemb + H1B + row * H1S + (tid % 14) * 4) = 0u;
    }

    // ---- phase 1: environment matrix d (-> DF A-frag slots, bf16) + stage B (h1) ----
    if (active) {
        const int nl = nlist[bid * NNEI + i];
        const float* nc = coord + ((size_t)f * NATOMS + (size_t)nl) * 3;
        float dx = nc[0] - cx, dy = nc[1] - cy, dz = nc[2] - cz;
        float rsq = dx * dx + dy * dy + dz * dz;
        float r = sqrtf(fmaxf(rsq, 1e-12f));
        float uu = (r - 0.5f) * (1.0f / 5.5f);
        float vv = uu * uu * uu * (uu * (-6.0f * uu + 15.0f) - 10.0f) + 1.0f;
        float sw = (r < 0.5f) ? 1.0f : ((r < 6.0f) ? vv : 0.0f);
        float rinv = frcp(r);
        float s = sw * rinv;
        float sor = s * rinv;
        const float* avg  = davg + ((size_t)at * NNEI + i) * 4;
        const float* stdp = dstd + ((size_t)at * NNEI + i) * 4;
        const float d0 = (s        - avg[0]) * frcp(stdp[0]);
        const float d1 = (sor * dx - avg[1]) * frcp(stdp[1]);
        const float d2 = (sor * dy - avg[2]) * frcp(stdp[2]);
        const float d3 = (sor * dz - avg[3]) * frcp(stdp[3]);

        // d -> DF A-frag slots: A[a][k=prow] = d[prow][a] (bf16)
        const unsigned int u01 = cvt_pk_bf16(d0, d1);
        const unsigned int u23 = cvt_pk_bf16(d2, d3);
        const int dbase = DFB + ((prow >> 5) << 8) + ((((prow >> 3) & 3) * 4) << 4)
                        + ((prow & 7) << 1);
        *reinterpret_cast<unsigned short*>(smemb + dbase +  0) = (unsigned short)u01;
        *reinterpret_cast<unsigned short*>(smemb + dbase + 16) = (unsigned short)(u01 >> 16);
        *reinterpret_cast<unsigned short*>(smemb + dbase + 32) = (unsigned short)u23;
        *reinterpret_cast<unsigned short*>(smemb + dbase + 48) = (unsigned short)(u23 >> 16);

        // stage B: h1 = tanh(x*W1 + b1) -> bf16 LDS row
        const float x = d0;
        #pragma unroll
        for (int c = 0; c < 3; ++c) {
            unsigned int u[4];
            #pragma unroll
            for (int p = 0; p < 4; ++p) {
                const float h0 = fast_tanh(fmaf(x, W1p[c * 8 + p * 2 + 0], b1p[c * 8 + p * 2 + 0]));
                const float h2 = fast_tanh(fmaf(x, W1p[c * 8 + p * 2 + 1], b1p[c * 8 + p * 2 + 1]));
                u[p] = cvt_pk_bf16(h0, h2);
            }
            uint4 w; w.x = u[0]; w.y = u[1]; w.z = u[2]; w.w = u[3];
            *reinterpret_cast<uint4*>(smemb + H1B + prow * H1S + c * 16) = w;
        }
    }

    __syncthreads();   // barrier 1: h1, DF ready

    // ---- stage C: X2 = (H1 @ S2) + tanh(H1 @ W2 + b2) via MFMA ----
    f32x4 accC[3][3], askC[3][3];
    #pragma unroll
    for (int mt = 0; mt < 3; ++mt)
        #pragma unroll
        for (int nt = 0; nt < 3; ++nt) {
            f32x4 c0; c0[0] = b2v[nt]; c0[1] = b2v[nt]; c0[2] = b2v[nt]; c0[3] = b2v[nt];
            accC[mt][nt] = c0;
            askC[mt][nt] = (f32x4){0.f, 0.f, 0.f, 0.f};
        }
    #pragma unroll
    for (int mt = 0; mt < 3; ++mt) {
        const int row = (wid * 3 + mt) * 16 + cl;
        // grp3 reads k=24..31 -> zeroed pad + next row head; W2/S2 frags zero for k>=24
        const short8 a = *reinterpret_cast<const short8*>(smemb + H1B + row * H1S + grp * 16);
        #pragma unroll
        for (int nt = 0; nt < 3; ++nt) {
            accC[mt][nt] = __builtin_amdgcn_mfma_f32_16x16x32_bf16(a, w2f[nt], accC[mt][nt], 0, 0, 0);
            askC[mt][nt] = __builtin_amdgcn_mfma_f32_16x16x32_bf16(a, sf2[nt], askC[mt][nt], 0, 0, 0);
        }
    }
    // epilogue C: x2 = h1skip + tanh(acc); write X2 bf16
    #pragma unroll
    for (int mt = 0; mt < 3; ++mt) {
        #pragma unroll
        for (int q = 0; q < 4; ++q) {
            const int r = (wid * 3 + mt) * 16 + grp * 4 + q;
            #pragma unroll
            for (int nt = 0; nt < 3; ++nt) {
                const float x2v = askC[mt][nt][q] + fast_tanh(accC[mt][nt][q]);
                *reinterpret_cast<unsigned short*>(smemb + X2B + r * X2S + 2 * (nt * 16 + cl)) =
                    (unsigned short)cvt_pk_bf16(x2v, x2v);
            }
        }
    }

    __syncthreads();   // barrier 2: X2 complete

    // ---- load A-frags (x2) for stage D ----
    const short8 zero8 = (short8){0,0,0,0,0,0,0,0};
    short8 a0[3], a1[3];
    #pragma unroll
    for (int mt = 0; mt < 3; ++mt) {
        const int row = (wid * 3 + mt) * 16 + cl;
        a0[mt] = *reinterpret_cast<const short8*>(smemb + X2B + row * X2S + grp * 16);
        short8 t = *reinterpret_cast<const short8*>(smemb + X2B + row * X2S + 64 + (grp & 1) * 16);
        a1[mt] = (grp < 2) ? t : zero8;   // zero k=48..63
    }

    __syncthreads();   // barrier 3: all A-frags loaded -> X2/H1 dead, GF writes safe

    // GF tail zero: ks=4, lanes 32..63 (k=144..159) of every ntg — one uint4/thread
    {
        const int ntg = tid / 32, l32 = tid & 31;
        uint4 z; z.x = 0u; z.y = 0u; z.z = 0u; z.w = 0u;
        *reinterpret_cast<uint4*>(smemb + GFB + ntg * GFS + 4096 + (32 + l32) * 16) = z;
    }

    // ---- stage D: acc_skip = X2 @ I48 (shared across passes), then 2 passes of W3 ----
    f32x4 askip[3][3];
    {
        short8 sf0[3], sf1[3];
        #pragma unroll
        for (int nt = 0; nt < 3; ++nt) {
            sf0[nt] = *reinterpret_cast<const short8*>(ws + WS_SF + (nt * 2 + 0) * 1024 + lane * 16);
            sf1[nt] = *reinterpret_cast<const short8*>(ws + WS_SF + (nt * 2 + 1) * 1024 + lane * 16);
        }
        #pragma unroll
        for (int mt = 0; mt < 3; ++mt)
            #pragma unroll
            for (int nt = 0; nt < 3; ++nt) {
                f32x4 t = (f32x4){0.f, 0.f, 0.f, 0.f};
                t = __builtin_amdgcn_mfma_f32_16x16x32_bf16(a0[mt], sf0[nt], t, 0, 0, 0);
                t = __builtin_amdgcn_mfma_f32_16x16x32_bf16(a1[mt], sf1[nt], t, 0, 0, 0);
                askip[mt][nt] = t;
            }
    }

    const unsigned char* w3p = ws + WS_W3F + tseg * 12288 + lane * 16;

    #pragma unroll
    for (int pass = 0; pass < 2; ++pass) {
        f32x4 acc[3][3];
        #pragma unroll
        for (int mt = 0; mt < 3; ++mt)
            #pragma unroll
            for (int ntl = 0; ntl < 3; ++ntl) {
                const float b = b3v[pass * 3 + ntl];
                f32x4 c0; c0[0] = b; c0[1] = b; c0[2] = b; c0[3] = b;
                acc[mt][ntl] = c0;
            }
        // double-buffered direct-global W3 B-frag loads (L2-resident)
        short8 nb0 = *reinterpret_cast<const short8*>(w3p + (pass * 3) * 2048);
        short8 nb1 = *reinterpret_cast<const short8*>(w3p + (pass * 3) * 2048 + 1024);
        #pragma unroll
        for (int ntl = 0; ntl < 3; ++ntl) {
            const short8 bk0 = nb0, bk1 = nb1;
            if (ntl < 2) {
                nb0 = *reinterpret_cast<const short8*>(w3p + (pass * 3 + ntl + 1) * 2048);
                nb1 = *reinterpret_cast<const short8*>(w3p + (pass * 3 + ntl + 1) * 2048 + 1024);
            }
            #pragma unroll
            for (int mt = 0; mt < 3; ++mt) {
                acc[mt][ntl] = __builtin_amdgcn_mfma_f32_16x16x32_bf16(a0[mt], bk0, acc[mt][ntl], 0, 0, 0);
                acc[mt][ntl] = __builtin_amdgcn_mfma_f32_16x16x32_bf16(a1[mt], bk1, acc[mt][ntl], 0, 0, 0);
            }
        }
        // epilogue: G = askip + tanh(acc) -> bf16 -> GF B-frag slots (uint2 each)
        #pragma unroll
        for (int mt = 0; mt < 3; ++mt) {
            const int row0 = (wid * 3 + mt) * 16 + grp * 4;
            const int ks = row0 >> 5;
            const int gp = (row0 >> 3) & 3;
            #pragma unroll
            for (int ntl = 0; ntl < 3; ++ntl) {
                const int ntg = pass * 3 + ntl;
                const float g0 = askip[mt][ntl][0] + fast_tanh(acc[mt][ntl][0]);
                const float g1 = askip[mt][ntl][1] + fast_tanh(acc[mt][ntl][1]);
                const float g2 = askip[mt][ntl][2] + fast_tanh(acc[mt][ntl][2]);
                const float g3 = askip[mt][ntl][3] + fast_tanh(acc[mt][ntl][3]);
                uint2 w;
                w.x = cvt_pk_bf16(g0, g1);
                w.y = cvt_pk_bf16(g2, g3);
                *reinterpret_cast<uint2*>(smemb + GFB + ntg * GFS + ks * 1024
                                          + ((gp * 16 + cl) << 4) + ((grp & 1) << 3)) = w;
            }
        }
    }

    __syncthreads();   // barrier 4: GF complete

    // ---- gr = d^T G via MFMA: C[a][m], K=160; wave handles 2 n-tiles ----
    short8 af[5];
    #pragma unroll
    for (int ks = 0; ks < 5; ++ks) {
        short8 v = zero8;
        if (cl < 4)
            v = *reinterpret_cast<const short8*>(smemb + DFB + (ks << 8) + ((grp * 4 + cl) << 4));
        af[ks] = v;
    }
    f32x4 racc[2];
    #pragma unroll
    for (int t = 0; t < 2; ++t) {
        const int ntg = wid * 2 + t;
        f32x4 r = (f32x4){0.f, 0.f, 0.f, 0.f};
        #pragma unroll
        for (int ks = 0; ks < 5; ++ks) {
            const short8 b = *reinterpret_cast<const short8*>(
                smemb + GFB + ntg * GFS + ks * 1024 + lane * 16);
            r = __builtin_amdgcn_mfma_f32_16x16x32_bf16(af[ks], b, r, 0, 0, 0);
        }
        racc[t] = r;
    }

    __syncthreads();   // barrier 5a: all GF/DF reads done -> GRB alias safe

    if (grp == 0) {
        const float inv = 1.0f / (float)NNEI;
        #pragma unroll
        for (int t = 0; t < 2; ++t) {
            const int ntg = wid * 2 + t;
            #pragma unroll
            for (int q = 0; q < 4; ++q)
                *reinterpret_cast<float*>(smemb + GRBB + (q * 96 + ntg * 16 + cl) * 4) =
                    racc[t][q] * inv;
        }
    }

    __syncthreads();   // barrier 5b: gr ready

    // ---- phase 3: D[m][k] = sum_a gr[a][m]*gr[a][k], k<8 ----
    {
        const float* gr = reinterpret_cast<const float*>(smemb + GRBB);
        const size_t base = (size_t)bid * 768;
        #pragma unroll
        for (int rep = 0; rep < 4; ++rep) {
            const int o  = tid + rep * 192;
            const int mm = o >> 3;
            const int kk = o & 7;
            float a0v = 0.f;
            #pragma unroll
            for (int a = 0; a < 4; ++a)
                a0v = fmaf(gr[a * 96 + mm], gr[a * 96 + kk], a0v);
            out[base + o] = a0v;
        }
    }
}

extern "C" void kernel_launch(void* const* d_in, const int* in_sizes, int n_in,
                              void* d_out, int out_size, void* d_ws, size_t ws_size,
                              hipStream_t stream) {
    const float* coord = (const float*)d_in[0];
    const float* davg  = (const float*)d_in[1];
    const float* dstd  = (const float*)d_in[2];
    const float* W1    = (const float*)d_in[3];
    const float* b1    = (const float*)d_in[4];
    const float* W2    = (const float*)d_in[5];
    const float* b2    = (const float*)d_in[6];
    const float* W3    = (const float*)d_in[7];
    const float* b3    = (const float*)d_in[8];
    const int*   atype = (const int*)d_in[9];
    const int*   nlist = (const int*)d_in[10];
    float* out = (float*)d_out;
    unsigned char* ws = (unsigned char*)d_ws;

    prep_kernel<<<dim3(11), dim3(256), 0, stream>>>(W2, W3, ws);
    descrpt_sea_kernel<<<dim3(NFRAME * NATOMS), dim3(192), 0, stream>>>(
        coord, davg, dstd, W1, b1, W2, b2, W3, b3, atype, nlist, ws, out);
}

// Round 9
// 95.759 us; speedup vs baseline: 5.1490x; 1.0081x over previous
//
#include <hip/hip_runtime.h>

#define NFRAME 2
#define NATOMS 4096
#define NNEI 138
#define SEL0 46
#define N1 24
#define N2 48
#define N3 96

// ---- workspace layout (BYTE offsets) ----
#define WS_W2F 0        // [2 seg][3 nt][64 lane][16B] bf16 W2 B-frags = 6144 B
#define WS_W3F 8192     // [2 seg][6 nt][2 ks][64 lane][16B] bf16 W3 B-frags = 24576 B
#define WS_SF  32768    // [3 ntl][2 ks][64 lane][16B] identity-48 B-frags = 6144 B
#define WS_SF2 38912    // [3 ntl][64 lane][16B] concat-24 B-frags = 3072 B

// ---- LDS layout (BYTE offsets) ----
// GF: G in B-frag layout [6 ntg][5 ks][64 lane][16B] = 30720 B.
//   Aliases X2 (0..14976) + H1 (14976..23096) + spare — both dead after barrier3.
#define GFB 0
#define GFS 5120        // per-ntg stride
#define X2B 0           // 144 rows x 104 B bf16 x2
#define X2S 104
#define H1B 14976       // 145 rows x 56 B bf16 h1 (48 B + 8 B zero pad; row 144 phantom)
#define H1S 56
#define DFB 30720       // d in A-frag layout, compact cl<4: [5 ks][16 slot][16B] = 1280 B
#define GRBB 0          // gr 4x96 f32 = 1536 B, aliases GF ntg0 after barrier5a
#define SMEM_BYTES 32000 // -> 5 blocks/CU

using short8 = __attribute__((ext_vector_type(8))) short;
using f32x4  = __attribute__((ext_vector_type(4))) float;

__device__ __forceinline__ float fexp2(float x) {
#if __has_builtin(__builtin_amdgcn_exp2f)
    return __builtin_amdgcn_exp2f(x);
#else
    return exp2f(x);
#endif
}
__device__ __forceinline__ float frcp(float x) {
#if __has_builtin(__builtin_amdgcn_rcpf)
    return __builtin_amdgcn_rcpf(x);
#else
    return 1.0f / x;
#endif
}
// tanh(x) = 1 - 2/(exp(2x)+1); saturates for |x| large
__device__ __forceinline__ float fast_tanh(float x) {
    float e = fexp2(x * 2.8853900817779268f);
    return 1.0f - 2.0f * frcp(e + 1.0f);
}
// RNE f32 -> bf16 bits (prep kernel)
__device__ __forceinline__ unsigned int f2bf(float f) {
    unsigned int u = __float_as_uint(f);
    return (u + 0x7fffu + ((u >> 16) & 1u)) >> 16;
}
// hot path: 1-instr packed convert, lo = bf16(a), hi = bf16(b)
__device__ __forceinline__ unsigned int cvt_pk_bf16(float a, float b) {
    unsigned int r;
    asm("v_cvt_pk_bf16_f32 %0, %1, %2" : "=v"(r) : "v"(a), "v"(b));
    return r;
}

// ---- pre-kernel: pack W2/W3/S/S2 into bf16 fragment-major B-operand layouts ----
__global__ void prep_kernel(const float* __restrict__ W2,
                            const float* __restrict__ W3,
                            unsigned char* __restrict__ ws)
{
    const int c = blockIdx.x * 256 + threadIdx.x;   // 16B-chunk id
    const int lane = c & 63;
    const int cl = lane & 15, grp = lane >> 4;
    unsigned short v[8];
    if (c < 384) {                                  // W2 frags
        const int fi = c >> 6;                      // 0..5
        const int seg = fi / 3, nt = fi % 3;
        const int col = nt * 16 + cl;
        #pragma unroll
        for (int j = 0; j < 8; ++j) {
            const int k = grp * 8 + j;
            const float fv = (k < N1) ? W2[(seg * N1 + k) * N2 + col] : 0.0f;
            v[j] = (unsigned short)f2bf(fv);
        }
    } else if (c >= 512 && c < 2048) {              // W3 frags
        const int cc = c - 512;
        const int fi = cc >> 6;                     // 0..23
        const int seg = fi / 12, r = fi % 12, nt = r >> 1, ks = r & 1;
        const int col = nt * 16 + cl;
        #pragma unroll
        for (int j = 0; j < 8; ++j) {
            const int k = ks * 32 + grp * 8 + j;
            const float fv = (k < N2) ? W3[(seg * N2 + k) * N3 + col] : 0.0f;
            v[j] = (unsigned short)f2bf(fv);
        }
    } else if (c >= 2048 && c < 2432) {             // S: identity-48 (x2 skip)
        const int cc = c - 2048;
        const int fi = cc >> 6;                     // 0..5
        const int ntl = fi >> 1, ks = fi & 1;
        const int col = ntl * 16 + cl;
        #pragma unroll
        for (int j = 0; j < 8; ++j) {
            const int k = ks * 32 + grp * 8 + j;
            v[j] = (k == col) ? (unsigned short)0x3F80 : (unsigned short)0;
        }
    } else if (c >= 2432 && c < 2624) {             // S2: concat-24 (h1 skip)
        const int cc = c - 2432;
        const int ntl = cc >> 6;                    // 0..2
        const int col = ntl * 16 + cl;
        const int cm = (col < 24) ? col : (col - 24);
        #pragma unroll
        for (int j = 0; j < 8; ++j) {
            const int k = grp * 8 + j;
            v[j] = (k == cm) ? (unsigned short)0x3F80 : (unsigned short)0;
        }
    } else {
        return;
    }
    uint4 q;
    q.x = (unsigned)v[0] | ((unsigned)v[1] << 16);
    q.y = (unsigned)v[2] | ((unsigned)v[3] << 16);
    q.z = (unsigned)v[4] | ((unsigned)v[5] << 16);
    q.w = (unsigned)v[6] | ((unsigned)v[7] << 16);
    int off;
    if (c < 384)       off = WS_W2F + c * 16;
    else if (c < 2048) off = WS_W3F + (c - 512) * 16;
    else if (c < 2432) off = WS_SF  + (c - 2048) * 16;
    else               off = WS_SF2 + (c - 2432) * 16;
    *reinterpret_cast<uint4*>(ws + off) = q;
}

__global__ __launch_bounds__(192) __attribute__((amdgpu_waves_per_eu(4)))
void descrpt_sea_kernel(
    const float* __restrict__ coord,
    const float* __restrict__ davg,
    const float* __restrict__ dstd,
    const float* __restrict__ W1, const float* __restrict__ b1,
    const float* __restrict__ W2, const float* __restrict__ b2,
    const float* __restrict__ W3, const float* __restrict__ b3,
    const int* __restrict__ atype, const int* __restrict__ nlist,
    const unsigned char* __restrict__ ws,
    float* __restrict__ out)
{
    __shared__ float smemf[SMEM_BYTES / 4];
    unsigned char* smemb = reinterpret_cast<unsigned char*>(smemf);

    const int bid  = blockIdx.x;          // f*NATOMS + n
    const int f    = bid >> 12;
    const int tid  = threadIdx.x;
    const int wid  = tid >> 6;
    const int lane = tid & 63;
    const int cl   = lane & 15;
    const int grp  = lane >> 4;

    // lane -> neighbor; padded rows: seg0 -> 0..45 (pad 46,47), seg1 -> 48..139 (pad 140..143)
    int i;
    bool active;
    if (wid == 0)      { i = lane;             active = (lane < SEL0); }
    else if (wid == 1) { i = SEL0 + lane;      active = true; }
    else               { i = SEL0 + 64 + lane; active = (i < NNEI); }
    const int tseg = __builtin_amdgcn_readfirstlane((wid == 0) ? 0 : 1);
    const int prow = (i < SEL0) ? i : (i + 2);

    const float* b2p = b2 + tseg * N2;
    const float* b3p = b3 + tseg * N3;
    float b2v[3], b3v[6];
    #pragma unroll
    for (int nt = 0; nt < 3; ++nt) b2v[nt] = b2p[nt * 16 + cl];
    #pragma unroll
    for (int nt = 0; nt < 6; ++nt) b3v[nt] = b3p[nt * 16 + cl];

    const float cx = coord[bid * 3 + 0];
    const float cy = coord[bid * 3 + 1];
    const float cz = coord[bid * 3 + 2];
    const int at = atype[bid];

    const float* W1p = W1 + tseg * N1;
    const float* b1p = b1 + tseg * N1;

    // ---- zero fills (all disjoint from producer writes; no barrier needed) ----
    // DF slots with no producer: rows {46,47} u {140..159}, 4 a-slots each
    if (tid < 88) {
        const int t = tid >> 2;                          // 0..21
        const int row = (t < 2) ? (46 + t) : (138 + t);  // 46,47,140..159
        const int a = tid & 3;
        const int byte = DFB + ((row >> 5) << 8) + ((((row >> 3) & 3) * 4 + a) << 4)
                       + ((row & 7) << 1);
        *reinterpret_cast<unsigned short*>(smemb + byte) = 0;
    }
    // h1 row tails (8B at +48) for all 144 rows
    if (tid < 144)
        *reinterpret_cast<uint2*>(smemb + H1B + tid * H1S + 48) = (uint2){0u, 0u};
    // phantom row 144
    if (tid < 14)
        *reinterpret_cast<unsigned int*>(smemb + H1B + 144 * H1S + tid * 4) = 0u;
    // pad-atom h1 rows {46,47,140..143} fully zero (56 B = 14 words each)
    if (tid < 84) {
        const int ri = tid / 14;
        const int row = (ri < 2) ? (46 + ri) : (138 + ri);
        *reinterpret_cast<unsigned int*>(smemb + H1B + row * H1S + (tid % 14) * 4) = 0u;
    }

    // ---- phase 1: environment matrix d (-> DF A-frag slots, bf16) + stage B (h1) ----
    if (active) {
        const int nl = nlist[bid * NNEI + i];
        const float* nc = coord + ((size_t)f * NATOMS + (size_t)nl) * 3;
        float dx = nc[0] - cx, dy = nc[1] - cy, dz = nc[2] - cz;
        float rsq = dx * dx + dy * dy + dz * dz;
        float r = sqrtf(fmaxf(rsq, 1e-12f));
        float uu = (r - 0.5f) * (1.0f / 5.5f);
        float vv = uu * uu * uu * (uu * (-6.0f * uu + 15.0f) - 10.0f) + 1.0f;
        float sw = (r < 0.5f) ? 1.0f : ((r < 6.0f) ? vv : 0.0f);
        float rinv = frcp(r);
        float s = sw * rinv;
        float sor = s * rinv;
        const float* avg  = davg + ((size_t)at * NNEI + i) * 4;
        const float* stdp = dstd + ((size_t)at * NNEI + i) * 4;
        const float d0 = (s        - avg[0]) * frcp(stdp[0]);
        const float d1 = (sor * dx - avg[1]) * frcp(stdp[1]);
        const float d2 = (sor * dy - avg[2]) * frcp(stdp[2]);
        const float d3 = (sor * dz - avg[3]) * frcp(stdp[3]);

        // d -> DF A-frag slots: A[a][k=prow] = d[prow][a] (bf16)
        const unsigned int u01 = cvt_pk_bf16(d0, d1);
        const unsigned int u23 = cvt_pk_bf16(d2, d3);
        const int dbase = DFB + ((prow >> 5) << 8) + ((((prow >> 3) & 3) * 4) << 4)
                        + ((prow & 7) << 1);
        *reinterpret_cast<unsigned short*>(smemb + dbase +  0) = (unsigned short)u01;
        *reinterpret_cast<unsigned short*>(smemb + dbase + 16) = (unsigned short)(u01 >> 16);
        *reinterpret_cast<unsigned short*>(smemb + dbase + 32) = (unsigned short)u23;
        *reinterpret_cast<unsigned short*>(smemb + dbase + 48) = (unsigned short)(u23 >> 16);

        // stage B: h1 = tanh(x*W1 + b1) -> bf16 LDS row
        const float x = d0;
        #pragma unroll
        for (int c = 0; c < 3; ++c) {
            unsigned int u[4];
            #pragma unroll
            for (int p = 0; p < 4; ++p) {
                const float h0 = fast_tanh(fmaf(x, W1p[c * 8 + p * 2 + 0], b1p[c * 8 + p * 2 + 0]));
                const float h2 = fast_tanh(fmaf(x, W1p[c * 8 + p * 2 + 1], b1p[c * 8 + p * 2 + 1]));
                u[p] = cvt_pk_bf16(h0, h2);
            }
            uint4 w; w.x = u[0]; w.y = u[1]; w.z = u[2]; w.w = u[3];
            *reinterpret_cast<uint4*>(smemb + H1B + prow * H1S + c * 16) = w;
        }
    }

    __syncthreads();   // barrier 1: h1, DF ready

    // ---- stage C: X2 = (H1 @ S2) + tanh(H1 @ W2 + b2) via MFMA ----
    // nt-outer loop: live AGPR = acc[3]+ask[3] = 24 (was 72)
    short8 aC[3];
    #pragma unroll
    for (int mt = 0; mt < 3; ++mt) {
        const int row = (wid * 3 + mt) * 16 + cl;
        // grp3 reads k=24..31 -> zeroed pad + next row head; W2/S2 frags zero for k>=24
        aC[mt] = *reinterpret_cast<const short8*>(smemb + H1B + row * H1S + grp * 16);
    }
    #pragma unroll
    for (int nt = 0; nt < 3; ++nt) {
        const short8 wf = *reinterpret_cast<const short8*>(ws + WS_W2F + (tseg * 3 + nt) * 1024 + lane * 16);
        const short8 s2 = *reinterpret_cast<const short8*>(ws + WS_SF2 + nt * 1024 + lane * 16);
        f32x4 acc[3], ask[3];
        #pragma unroll
        for (int mt = 0; mt < 3; ++mt) {
            f32x4 c0; c0[0] = b2v[nt]; c0[1] = b2v[nt]; c0[2] = b2v[nt]; c0[3] = b2v[nt];
            acc[mt] = __builtin_amdgcn_mfma_f32_16x16x32_bf16(aC[mt], wf, c0, 0, 0, 0);
            ask[mt] = __builtin_amdgcn_mfma_f32_16x16x32_bf16(aC[mt], s2,
                         (f32x4){0.f, 0.f, 0.f, 0.f}, 0, 0, 0);
        }
        #pragma unroll
        for (int mt = 0; mt < 3; ++mt) {
            #pragma unroll
            for (int q = 0; q < 4; ++q) {
                const int r = (wid * 3 + mt) * 16 + grp * 4 + q;
                const float x2v = ask[mt][q] + fast_tanh(acc[mt][q]);
                *reinterpret_cast<unsigned short*>(smemb + X2B + r * X2S + 2 * (nt * 16 + cl)) =
                    (unsigned short)cvt_pk_bf16(x2v, x2v);
            }
        }
    }

    __syncthreads();   // barrier 2: X2 complete

    // ---- load A-frags (x2) for stage D ----
    const short8 zero8 = (short8){0,0,0,0,0,0,0,0};
    short8 a0[3], a1[3];
    #pragma unroll
    for (int mt = 0; mt < 3; ++mt) {
        const int row = (wid * 3 + mt) * 16 + cl;
        a0[mt] = *reinterpret_cast<const short8*>(smemb + X2B + row * X2S + grp * 16);
        short8 t = *reinterpret_cast<const short8*>(smemb + X2B + row * X2S + 64 + (grp & 1) * 16);
        a1[mt] = (grp < 2) ? t : zero8;   // zero k=48..63
    }

    __syncthreads();   // barrier 3: all A-frags loaded -> X2/H1 dead, GF writes safe

    // GF tail zero: ks=4, lanes 32..63 (k=144..159) of every ntg — one uint4/thread
    {
        const int ntg = tid / 32, l32 = tid & 31;
        uint4 z; z.x = 0u; z.y = 0u; z.z = 0u; z.w = 0u;
        *reinterpret_cast<uint4*>(smemb + GFB + ntg * GFS + 4096 + (32 + l32) * 16) = z;
    }

    // ---- stage D: ntl-outer, pass-inner; askip computed once per ntl, reused by both passes ----
    const unsigned char* w3p = ws + WS_W3F + tseg * 12288 + lane * 16;
    #pragma unroll
    for (int ntl = 0; ntl < 3; ++ntl) {
        // askip = X2 @ I48 slice (skip connection), shared by pass 0/1
        f32x4 askip[3];
        {
            const short8 sf0 = *reinterpret_cast<const short8*>(ws + WS_SF + (ntl * 2 + 0) * 1024 + lane * 16);
            const short8 sf1 = *reinterpret_cast<const short8*>(ws + WS_SF + (ntl * 2 + 1) * 1024 + lane * 16);
            #pragma unroll
            for (int mt = 0; mt < 3; ++mt) {
                f32x4 t = __builtin_amdgcn_mfma_f32_16x16x32_bf16(a0[mt], sf0,
                             (f32x4){0.f, 0.f, 0.f, 0.f}, 0, 0, 0);
                askip[mt] = __builtin_amdgcn_mfma_f32_16x16x32_bf16(a1[mt], sf1, t, 0, 0, 0);
            }
        }
        #pragma unroll
        for (int pass = 0; pass < 2; ++pass) {
            const int ntg = pass * 3 + ntl;
            const short8 bk0 = *reinterpret_cast<const short8*>(w3p + ntg * 2048);
            const short8 bk1 = *reinterpret_cast<const short8*>(w3p + ntg * 2048 + 1024);
            const float b = b3v[ntg];
            f32x4 acc[3];
            #pragma unroll
            for (int mt = 0; mt < 3; ++mt) {
                f32x4 c0; c0[0] = b; c0[1] = b; c0[2] = b; c0[3] = b;
                c0 = __builtin_amdgcn_mfma_f32_16x16x32_bf16(a0[mt], bk0, c0, 0, 0, 0);
                acc[mt] = __builtin_amdgcn_mfma_f32_16x16x32_bf16(a1[mt], bk1, c0, 0, 0, 0);
            }
            // epilogue: G = askip + tanh(acc) -> bf16 -> GF B-frag slots (uint2 each)
            #pragma unroll
            for (int mt = 0; mt < 3; ++mt) {
                const int row0 = (wid * 3 + mt) * 16 + grp * 4;
                const int ks = row0 >> 5;
                const int gp = (row0 >> 3) & 3;
                const float g0 = askip[mt][0] + fast_tanh(acc[mt][0]);
                const float g1 = askip[mt][1] + fast_tanh(acc[mt][1]);
                const float g2 = askip[mt][2] + fast_tanh(acc[mt][2]);
                const float g3 = askip[mt][3] + fast_tanh(acc[mt][3]);
                uint2 w;
                w.x = cvt_pk_bf16(g0, g1);
                w.y = cvt_pk_bf16(g2, g3);
                *reinterpret_cast<uint2*>(smemb + GFB + ntg * GFS + ks * 1024
                                          + ((gp * 16 + cl) << 4) + ((grp & 1) << 3)) = w;
            }
        }
    }

    __syncthreads();   // barrier 4: GF complete

    // ---- gr = d^T G via MFMA: C[a][m], K=160; wave handles 2 n-tiles ----
    short8 af[5];
    #pragma unroll
    for (int ks = 0; ks < 5; ++ks) {
        short8 v = zero8;
        if (cl < 4)
            v = *reinterpret_cast<const short8*>(smemb + DFB + (ks << 8) + ((grp * 4 + cl) << 4));
        af[ks] = v;
    }
    f32x4 racc[2];
    #pragma unroll
    for (int t = 0; t < 2; ++t) {
        const int ntg = wid * 2 + t;
        f32x4 r = (f32x4){0.f, 0.f, 0.f, 0.f};
        #pragma unroll
        for (int ks = 0; ks < 5; ++ks) {
            const short8 b = *reinterpret_cast<const short8*>(
                smemb + GFB + ntg * GFS + ks * 1024 + lane * 16);
            r = __builtin_amdgcn_mfma_f32_16x16x32_bf16(af[ks], b, r, 0, 0, 0);
        }
        racc[t] = r;
    }

    __syncthreads();   // barrier 5a: all GF/DF reads done -> GRB alias safe

    if (grp == 0) {
        const float inv = 1.0f / (float)NNEI;
        #pragma unroll
        for (int t = 0; t < 2; ++t) {
            const int ntg = wid * 2 + t;
            #pragma unroll
            for (int q = 0; q < 4; ++q)
                *reinterpret_cast<float*>(smemb + GRBB + (q * 96 + ntg * 16 + cl) * 4) =
                    racc[t][q] * inv;
        }
    }

    __syncthreads();   // barrier 5b: gr ready

    // ---- phase 3: D[m][k] = sum_a gr[a][m]*gr[a][k], k<8 ----
    {
        const float* gr = reinterpret_cast<const float*>(smemb + GRBB);
        const size_t base = (size_t)bid * 768;
        #pragma unroll
        for (int rep = 0; rep < 4; ++rep) {
            const int o  = tid + rep * 192;
            const int mm = o >> 3;
            const int kk = o & 7;
            float a0v = 0.f;
            #pragma unroll
            for (int a = 0; a < 4; ++a)
                a0v = fmaf(gr[a * 96 + mm], gr[a * 96 + kk], a0v);
            out[base + o] = a0v;
        }
    }
}

extern "C" void kernel_launch(void* const* d_in, const int* in_sizes, int n_in,
                              void* d_out, int out_size, void* d_ws, size_t ws_size,
                              hipStream_t stream) {
    const float* coord = (const float*)d_in[0];
    const float* davg  = (const float*)d_in[1];
    const float* dstd  = (const float*)d_in[2];
    const float* W1    = (const float*)d_in[3];
    const float* b1    = (const float*)d_in[4];
    const float* W2    = (const float*)d_in[5];
    const float* b2    = (const float*)d_in[6];
    const float* W3    = (const float*)d_in[7];
    const float* b3    = (const float*)d_in[8];
    const int*   atype = (const int*)d_in[9];
    const int*   nlist = (const int*)d_in[10];
    float* out = (float*)d_out;
    unsigned char* ws = (unsigned char*)d_ws;

    prep_kernel<<<dim3(11), dim3(256), 0, stream>>>(W2, W3, ws);
    descrpt_sea_kernel<<<dim3(NFRAME * NATOMS), dim3(192), 0, stream>>>(
        coord, davg, dstd, W1, b1, W2, b2, W3, b3, atype, nlist, ws, out);
}